// Round 14
// baseline (161.509 us; speedup 1.0000x reference)
//
#include <hip/hip_runtime.h>
#include <stdint.h>

#define T_Q   2048
#define N_REF 16384
#define DIM   768
#define KP2   1536        // packed K cols: [hi | lo]
#define NT    24          // K = 768 = 24 tiles of 32 (hi limb only)
#define NL    128         // partial top-4 lists per query (128-col block stripes)
#define NDB   (DIM / 64)  // 12 d-blocks for partial r2

using f16   = _Float16;
using f16x4 = __attribute__((ext_vector_type(4))) _Float16;
using f16x8 = __attribute__((ext_vector_type(8))) _Float16;
using f32x4 = __attribute__((ext_vector_type(4))) float;
typedef unsigned long long u64;

// ---------- exact-path lexicographic top-4 (float score, int idx) ----------
__device__ __forceinline__ bool lex_less(float sa, int ia, float sb, int ib) {
  return (sa < sb) || (sa == sb && ia < ib);
}
#define CE_PAIR(s0, i0, s1, i1)                                        \
  { if (lex_less(s1, i1, s0, i0)) { float _ts = s0; s0 = s1; s1 = _ts; \
                                    int _ti = i0; i0 = i1; i1 = _ti; } }
#define PICKMIN(as, ai, bs, bi, rs, ri)                   \
  { if (lex_less(bs, bi, as, ai)) { rs = bs; ri = bi; }   \
    else                          { rs = as; ri = ai; } }

__device__ __forceinline__ void insert4(float s[4], int id[4], float sc, int n) {
  if (lex_less(sc, n, s[3], id[3])) {
    s[3] = sc; id[3] = n;
    CE_PAIR(s[2], id[2], s[3], id[3]);
    CE_PAIR(s[1], id[1], s[2], id[2]);
    CE_PAIR(s[0], id[0], s[1], id[1]);
  }
}
__device__ __forceinline__ void merge_top4(float s[4], int id[4],
                                           const float os[4], const int oid[4]) {
  float l0, l1, l2, l3; int j0, j1, j2, j3;
  PICKMIN(s[0], id[0], os[3], oid[3], l0, j0);
  PICKMIN(s[1], id[1], os[2], oid[2], l1, j1);
  PICKMIN(s[2], id[2], os[1], oid[1], l2, j2);
  PICKMIN(s[3], id[3], os[0], oid[0], l3, j3);
  CE_PAIR(l0, j0, l2, j2);
  CE_PAIR(l1, j1, l3, j3);
  CE_PAIR(l0, j0, l1, j1);
  CE_PAIR(l2, j2, l3, j3);
  s[0] = l0; s[1] = l1; s[2] = l2; s[3] = l3;
  id[0] = j0; id[1] = j1; id[2] = j2; id[3] = j3;
}

// ---------- packed-u64 ranking: (sortable_score32 << 32) | col ----------
// ascending u64 == ascending (score, col) lex. Verified exact in r12 (absmax 0).
__device__ __forceinline__ uint32_t fsort32(float f) {
  uint32_t u = __float_as_uint(f);
  return ((int)u < 0) ? ~u : (u | 0x80000000u);
}
__device__ __forceinline__ void ins4u(u64 s[4], u64 c) {
  if (c < s[3]) {
    s[3] = c;
    if (s[3] < s[2]) { u64 t = s[2]; s[2] = s[3]; s[3] = t; }
    if (s[2] < s[1]) { u64 t = s[1]; s[1] = s[2]; s[2] = t; }
    if (s[1] < s[0]) { u64 t = s[0]; s[0] = s[1]; s[1] = t; }
  }
}
#define CEU(a, b) { u64 _mn = (a) < (b) ? (a) : (b); \
                    u64 _mx = (a) < (b) ? (b) : (a); (a) = _mn; (b) = _mx; }
__device__ __forceinline__ void merge4u(u64 s[4], const u64 o[4]) {
  u64 l0 = s[0] < o[3] ? s[0] : o[3];
  u64 l1 = s[1] < o[2] ? s[1] : o[2];
  u64 l2 = s[2] < o[1] ? s[2] : o[1];
  u64 l3 = s[3] < o[0] ? s[3] : o[0];
  CEU(l0, l2); CEU(l1, l3); CEU(l0, l1); CEU(l2, l3);
  s[0] = l0; s[1] = l1; s[2] = l2; s[3] = l3;
}
__device__ __forceinline__ void merge8u(u64 s[8], const u64 o[8]) {
  u64 l0 = s[0] < o[7] ? s[0] : o[7];
  u64 l1 = s[1] < o[6] ? s[1] : o[6];
  u64 l2 = s[2] < o[5] ? s[2] : o[5];
  u64 l3 = s[3] < o[4] ? s[3] : o[4];
  u64 l4 = s[4] < o[3] ? s[4] : o[3];
  u64 l5 = s[5] < o[2] ? s[5] : o[2];
  u64 l6 = s[6] < o[1] ? s[6] : o[1];
  u64 l7 = s[7] < o[0] ? s[7] : o[0];
  CEU(l0, l4); CEU(l1, l5); CEU(l2, l6); CEU(l3, l7);
  CEU(l0, l2); CEU(l1, l3); CEU(l4, l6); CEU(l5, l7);
  CEU(l0, l1); CEU(l2, l3); CEU(l4, l5); CEU(l6, l7);
  s[0]=l0; s[1]=l1; s[2]=l2; s[3]=l3; s[4]=l4; s[5]=l5; s[6]=l6; s[7]=l7;
}

__device__ __forceinline__ void gl_lds16(const void* g, void* l) {
  __builtin_amdgcn_global_load_lds((const __attribute__((address_space(1))) uint32_t*)g,
                                   (__attribute__((address_space(3))) uint32_t*)l, 16, 0, 0);
}

// ---------- transpose + f16 hi/lo split for X: in[D][W] -> out[W][1536] ----------
__global__ __launch_bounds__(256)
void tsplit_kernel(const float* __restrict__ in, f16* __restrict__ out, int W) {
  __shared__ f16 lh[64][66], ll[64][66];
  const int c0 = blockIdx.x * 64, d0 = blockIdx.y * 64;
  const int q = threadIdx.x & 15, p = threadIdx.x >> 4;
#pragma unroll
  for (int i = 0; i < 4; ++i) {
    const int dl = p + i * 16;
    const float4 v = *(const float4*)&in[(size_t)(d0 + dl) * W + c0 + q * 4];
    const f16 h0 = (f16)v.x, h1 = (f16)v.y, h2 = (f16)v.z, h3 = (f16)v.w;
    lh[q * 4 + 0][dl] = h0; ll[q * 4 + 0][dl] = (f16)(v.x - (float)h0);
    lh[q * 4 + 1][dl] = h1; ll[q * 4 + 1][dl] = (f16)(v.y - (float)h1);
    lh[q * 4 + 2][dl] = h2; ll[q * 4 + 2][dl] = (f16)(v.z - (float)h2);
    lh[q * 4 + 3][dl] = h3; ll[q * 4 + 3][dl] = (f16)(v.w - (float)h3);
  }
  __syncthreads();
  const int rl = threadIdx.x >> 2, seg = threadIdx.x & 3;
  f16* rowo = out + (size_t)(c0 + rl) * KP2 + d0;
#pragma unroll
  for (int j = 0; j < 4; ++j) {
    const int dd = seg * 16 + j * 4;
    f16x4 vh = *(const f16x4*)&lh[rl][dd];
    f16x4 vl = *(const f16x4*)&ll[rl][dd];
    *(f16x4*)&rowo[dd] = vh;
    *(f16x4*)&rowo[768 + dd] = vl;
  }
}

// ---------- tsplit for R + PARTIAL r2 per d-block (full 3072-block grid) ----------
__global__ __launch_bounds__(256)
void tsplitR_kernel(const float* __restrict__ in, f16* __restrict__ out,
                    float* __restrict__ r2p) {
  __shared__ f16 lh[64][66], ll[64][66];
  const int c0 = blockIdx.x * 64, d0 = blockIdx.y * 64;
  const int q = threadIdx.x & 15, p = threadIdx.x >> 4;
  float a0 = 0.f, a1 = 0.f, a2 = 0.f, a3 = 0.f;
#pragma unroll
  for (int i = 0; i < 4; ++i) {
    const int dl = p + i * 16;
    const float4 v = *(const float4*)&in[(size_t)(d0 + dl) * N_REF + c0 + q * 4];
    const f16 h0 = (f16)v.x, h1 = (f16)v.y, h2 = (f16)v.z, h3 = (f16)v.w;
    lh[q * 4 + 0][dl] = h0; ll[q * 4 + 0][dl] = (f16)(v.x - (float)h0);
    lh[q * 4 + 1][dl] = h1; ll[q * 4 + 1][dl] = (f16)(v.y - (float)h1);
    lh[q * 4 + 2][dl] = h2; ll[q * 4 + 2][dl] = (f16)(v.z - (float)h2);
    lh[q * 4 + 3][dl] = h3; ll[q * 4 + 3][dl] = (f16)(v.w - (float)h3);
    a0 = fmaf(v.x, v.x, a0); a1 = fmaf(v.y, v.y, a1);
    a2 = fmaf(v.z, v.z, a2); a3 = fmaf(v.w, v.w, a3);
  }
  __syncthreads();
  const int rl = threadIdx.x >> 2, seg = threadIdx.x & 3;
  f16* rowo = out + (size_t)(c0 + rl) * KP2 + d0;
#pragma unroll
  for (int j = 0; j < 4; ++j) {
    const int dd = seg * 16 + j * 4;
    f16x4 vh = *(const f16x4*)&lh[rl][dd];
    f16x4 vl = *(const f16x4*)&ll[rl][dd];
    *(f16x4*)&rowo[dd] = vh;
    *(f16x4*)&rowo[768 + dd] = vl;
  }
  // partial r2 over this block's 64 d's (deterministic fixed-order reduce)
  __syncthreads();
  float* sq = (float*)lh;   // 16 x 64 f32 = 4 KB, lh no longer needed
  sq[p * 64 + q * 4 + 0] = a0;
  sq[p * 64 + q * 4 + 1] = a1;
  sq[p * 64 + q * 4 + 2] = a2;
  sq[p * 64 + q * 4 + 3] = a3;
  __syncthreads();
  if (threadIdx.x < 64) {
    float s = 0.f;
#pragma unroll
    for (int pp = 0; pp < 16; ++pp) s += sq[pp * 64 + threadIdx.x];
    r2p[(size_t)blockIdx.y * N_REF + c0 + threadIdx.x] = s;
  }
}

// ---------- sum 12 partials -> r2 (deterministic order) ----------
__global__ __launch_bounds__(256)
void r2sum_kernel(const float* __restrict__ r2p, float* __restrict__ r2) {
  const int t = blockIdx.x * 256 + threadIdx.x;
  float s = 0.f;
#pragma unroll
  for (int k = 0; k < NDB; ++k) s += r2p[(size_t)k * N_REF + t];
  r2[t] = s;
}

// ---------- m97-geometry 128x128 f16-hi MFMA GEMM + fused approx top-4 ----------
// K-loop is r11-verbatim (104 us). Epilogue: u64-packed lists (r12-verified),
// cross-wn in-block merge -> NL=128 lists/query (halves plist + selres work).
__global__ __launch_bounds__(256, 2)
void mfma128_topk_kernel(const f16* __restrict__ A2, const f16* __restrict__ B2,
                         const float* __restrict__ r2g, u64* __restrict__ plist) {
  __shared__ __align__(16) char smem[33792];
  const int tid  = threadIdx.x;
  const int lane = tid & 63, wid = tid >> 6;
  const int wm = wid >> 1, wn = wid & 1;
  const int ln15 = lane & 15, g4 = lane >> 4;

  const int flat = (int)blockIdx.x;
  const int jj = flat >> 3;
  const int bx = (flat & 7) * 16 + (jj & 15);  // 0..127
  const int by = jj >> 4;                      // 0..15
  const int m0 = by * 128, n0 = bx * 128;

  const int s0 = tid, s1 = tid + 256;
  const int r0 = s0 >> 2, r1 = s1 >> 2;
  const int c0b = (((s0 & 3) ^ ((s0 >> 3) & 3)) << 4);
  const int c1b = (((s1 & 3) ^ ((s1 >> 3) & 3)) << 4);
  const char* gA0 = (const char*)(A2 + (size_t)(m0 + r0) * KP2) + c0b;
  const char* gA1 = (const char*)(A2 + (size_t)(m0 + r1) * KP2) + c1b;
  const char* gB0 = (const char*)(B2 + (size_t)(n0 + r0) * KP2) + c0b;
  const char* gB1 = (const char*)(B2 + (size_t)(n0 + r1) * KP2) + c1b;
  const int l0 = s0 * 16, l1 = s1 * 16;

#define STAGE_A(bufo, kbyte)                                     \
  { gl_lds16(gA0 + (kbyte), smem + (bufo) + l0);                 \
    gl_lds16(gA1 + (kbyte), smem + (bufo) + l1); }
#define STAGE_B(bufo, kbyte)                                     \
  { gl_lds16(gB0 + (kbyte), smem + (bufo) + 8192 + l0);          \
    gl_lds16(gB1 + (kbyte), smem + (bufo) + 8192 + l1); }

  const int cswz = ((g4 ^ ((ln15 >> 1) & 3)) << 4);
  int offA[4], offB[4];
#pragma unroll
  for (int mi = 0; mi < 4; ++mi) offA[mi] = (wm * 64 + mi * 16 + ln15) * 64 + cswz;
#pragma unroll
  for (int ni = 0; ni < 4; ++ni) offB[ni] = 8192 + (wn * 64 + ni * 16 + ln15) * 64 + cswz;

  f32x4 acc[4][4] = {};

  STAGE_A(0, 0);
  STAGE_B(0, 0);

  for (int kt = 0; kt < NT; ++kt) {
    const int dbuf = (kt & 1) << 14;
    const int sdb  = ((kt + 1) & 1) << 14;
    const int ktn = (kt + 1 < NT) ? kt + 1 : NT - 1;

    STAGE_A(sdb, ktn * 64);
    STAGE_B(sdb, ktn * 64);
    asm volatile("s_waitcnt vmcnt(4)" ::: "memory");
    asm volatile("s_barrier" ::: "memory");

    f16x8 a[4], b[4];
    a[0] = *(const f16x8*)(smem + dbuf + offA[0]);
    b[0] = *(const f16x8*)(smem + dbuf + offB[0]);
    a[1] = *(const f16x8*)(smem + dbuf + offA[1]);
    b[1] = *(const f16x8*)(smem + dbuf + offB[1]);
    a[2] = *(const f16x8*)(smem + dbuf + offA[2]);
    b[2] = *(const f16x8*)(smem + dbuf + offB[2]);
    a[3] = *(const f16x8*)(smem + dbuf + offA[3]);
    b[3] = *(const f16x8*)(smem + dbuf + offB[3]);

    __builtin_amdgcn_s_setprio(1);
#pragma unroll
    for (int mi = 0; mi < 4; ++mi)
#pragma unroll
      for (int ni = 0; ni < 4; ++ni)
        acc[mi][ni] = __builtin_amdgcn_mfma_f32_16x16x32_f16(a[mi], b[ni], acc[mi][ni], 0, 0, 0);
    __builtin_amdgcn_s_setprio(0);
    asm volatile("s_barrier" ::: "memory");
  }

  asm volatile("s_waitcnt vmcnt(0)" ::: "memory");
  __syncthreads();

  // ---- epilogue: scatter sortable-u32, per-row u64 top-4 per 64-col stripe ----
  float rv[4];
#pragma unroll
  for (int ni = 0; ni < 4; ++ni) rv[ni] = r2g[n0 + wn * 64 + ni * 16 + ln15];
  uint32_t* swu = (uint32_t*)smem + wid * 2112;   // [32][66] u32, wave-private
  const int rr = lane >> 1, hh = lane & 1;
  u64 keep[2][4];
#pragma unroll
  for (int P = 0; P < 2; ++P) {
#pragma unroll
    for (int mh = 0; mh < 2; ++mh)
#pragma unroll
      for (int ni = 0; ni < 4; ++ni)
#pragma unroll
        for (int r = 0; r < 4; ++r) {
          const int row_l = mh * 16 + g4 * 4 + r;   // C/D: col=lane&15, row=(lane>>4)*4+reg
          swu[row_l * 66 + ni * 16 + ln15] = fsort32(rv[ni] - 2.0f * acc[2 * P + mh][ni][r]);
        }
    asm volatile("s_waitcnt lgkmcnt(0)" ::: "memory");
    __builtin_amdgcn_sched_barrier(0);
    u64 s[4] = {~0ull, ~0ull, ~0ull, ~0ull};
    const uint32_t* rowp = swu + rr * 66 + hh * 32;
    const uint32_t cb = (uint32_t)(n0 + wn * 64 + hh * 32);
#pragma unroll
    for (int j = 0; j < 16; ++j) {
      const uint2 v = *(const uint2*)(rowp + j * 2);
      ins4u(s, ((u64)v.x << 32) | (cb + j * 2));
      ins4u(s, ((u64)v.y << 32) | (cb + j * 2 + 1));
    }
    u64 os[4];
#pragma unroll
    for (int j = 0; j < 4; ++j) os[j] = __shfl_xor((u64)s[j], 1);
    merge4u(s, os);
#pragma unroll
    for (int j = 0; j < 4; ++j) keep[P][j] = s[j];
    asm volatile("s_waitcnt lgkmcnt(0)" ::: "memory");
  }

  // ---- cross-wn merge: one 4-list per query row per block (NL = 128) ----
  __syncthreads();                      // all waves done with their swu regions
  u64* lbuf = (u64*)smem;               // [128 rows][4] u64 = 4 KB
  if (wn == 1 && hh == 0) {
#pragma unroll
    for (int P = 0; P < 2; ++P) {
      const int lrow = wm * 64 + P * 32 + rr;
#pragma unroll
      for (int j = 0; j < 4; ++j) lbuf[lrow * 4 + j] = keep[P][j];
    }
  }
  __syncthreads();
  if (wn == 0 && hh == 0) {
#pragma unroll
    for (int P = 0; P < 2; ++P) {
      const int lrow = wm * 64 + P * 32 + rr;
      u64 o[4];
#pragma unroll
      for (int j = 0; j < 4; ++j) o[j] = lbuf[lrow * 4 + j];
      merge4u(keep[P], o);
      u64* dst = plist + ((size_t)(m0 + lrow) * NL + bx) * 4;
#pragma unroll
      for (int j = 0; j < 4; ++j) dst[j] = keep[P][j];
    }
  }
#undef STAGE_A
#undef STAGE_B
}

// ---------- fused: merge NL lists -> approx top-8 -> exact rescore -> top-4 ----------
__global__ __launch_bounds__(64)
void selres_kernel(const u64* __restrict__ plist,
                   const f16* __restrict__ A2, const f16* __restrict__ B2,
                   const float* __restrict__ r2, int* __restrict__ final4) {
  const int t = blockIdx.x, lane = threadIdx.x;
  u64 s[8];
#pragma unroll
  for (int j = 0; j < 8; ++j) s[j] = ~0ull;
#pragma unroll
  for (int li = 0; li < 2; ++li) {
    const u64* src = plist + ((size_t)t * NL + lane * 2 + li) * 4;
    u64 o[8] = {src[0], src[1], src[2], src[3], ~0ull, ~0ull, ~0ull, ~0ull};
    merge8u(s, o);
  }
#pragma unroll
  for (int mask = 1; mask < 64; mask <<= 1) {
    u64 o[8];
#pragma unroll
    for (int j = 0; j < 8; ++j) o[j] = __shfl_xor((u64)s[j], mask);
    merge8u(s, o);
  }
  // all lanes hold the same approx top-8; exact split-f16 rescore
  int cid[8];
#pragma unroll
  for (int j = 0; j < 8; ++j) cid[j] = (int)(uint32_t)s[j];
  const f16* xrow = A2 + (size_t)t * KP2;
  float xh[12], xl[12];
#pragma unroll
  for (int k = 0; k < 12; ++k) {
    xh[k] = (float)xrow[lane + 64 * k];
    xl[k] = (float)xrow[768 + lane + 64 * k];
  }
  float sc[8];
#pragma unroll
  for (int j = 0; j < 8; ++j) {
    const f16* rrow = B2 + (size_t)cid[j] * KP2;
    float acc = 0.f;
#pragma unroll
    for (int k = 0; k < 12; ++k) {
      const float rh = (float)rrow[lane + 64 * k];
      const float rl = (float)rrow[768 + lane + 64 * k];
      acc = fmaf(xh[k], rh, acc);
      acc = fmaf(xh[k], rl, acc);
      acc = fmaf(xl[k], rh, acc);
    }
#pragma unroll
    for (int m = 1; m < 64; m <<= 1) acc += __shfl_xor(acc, m);
    sc[j] = r2[cid[j]] - 2.0f * acc;
  }
  if (lane == 0) {
    float s4[4] = {1e30f, 1e30f, 1e30f, 1e30f};
    int   i4[4] = {0x7fffffff, 0x7fffffff, 0x7fffffff, 0x7fffffff};
#pragma unroll
    for (int j = 0; j < 8; ++j) insert4(s4, i4, sc[j], cid[j]);
    int4 o; o.x = i4[0]; o.y = i4[1]; o.z = i4[2]; o.w = i4[3];
    *(int4*)&final4[t * 4] = o;
  }
}

// ---------- gather from B2 rows (coalesced) + LDS transpose -> out [d][T] ----------
__global__ __launch_bounds__(256)
void gatherB2_kernel(const f16* __restrict__ B2, const int* __restrict__ final4,
                     float* __restrict__ out) {
  __shared__ int ids[64][4];
  __shared__ float tr[64][129];
  const int tid = threadIdx.x;
  const int t0 = blockIdx.x * 64;
  const int d0 = blockIdx.y * 128;
  ((int*)ids)[tid] = final4[t0 * 4 + tid];
  __syncthreads();

  const int q = tid >> 2, dp = tid & 3;
  float a[32];
#pragma unroll
  for (int k = 0; k < 32; ++k) a[k] = 0.f;
#pragma unroll
  for (int j = 0; j < 4; ++j) {
    const f16* row = B2 + (size_t)ids[q][j] * KP2 + d0 + dp * 32;
#pragma unroll
    for (int v = 0; v < 4; ++v) {
      const f16x8 h = *(const f16x8*)(row + v * 8);
      const f16x8 l = *(const f16x8*)(row + 768 + v * 8);
#pragma unroll
      for (int e = 0; e < 8; ++e) a[v * 8 + e] += (float)h[e] + (float)l[e];
    }
  }
#pragma unroll
  for (int k = 0; k < 32; ++k) tr[q][dp * 32 + k] = 0.25f * a[k];
  __syncthreads();

  const int dd = tid >> 1, hf = tid & 1;
  float* orow = out + (size_t)(d0 + dd) * T_Q + t0 + hf * 32;
#pragma unroll
  for (int k = 0; k < 8; ++k) {
    float4 v4;
    v4.x = tr[hf * 32 + k * 4 + 0][dd];
    v4.y = tr[hf * 32 + k * 4 + 1][dd];
    v4.z = tr[hf * 32 + k * 4 + 2][dd];
    v4.w = tr[hf * 32 + k * 4 + 3][dd];
    *(float4*)(orow + k * 4) = v4;
  }
}

// ---------- fallback fp32 pipeline (round-1, known correct) ----------
__global__ __launch_bounds__(256)
void r2_kernel(const float* __restrict__ R, float* __restrict__ r2) {
  __shared__ float red[256];
  const int lane = threadIdx.x & 63;
  const int dg   = threadIdx.x >> 6;
  const int n    = blockIdx.x * 64 + lane;
  float acc = 0.f;
  const int d0 = dg * (DIM / 4), d1 = d0 + (DIM / 4);
  for (int d = d0; d < d1; ++d) {
    float v = R[(size_t)d * N_REF + n];
    acc += v * v;
  }
  red[threadIdx.x] = acc;
  __syncthreads();
  if (threadIdx.x < 64)
    r2[n] = red[lane] + red[lane + 64] + red[lane + 128] + red[lane + 192];
}

__global__ __launch_bounds__(256)
void gather_kernel(const float* __restrict__ R, const int* __restrict__ final4,
                   float* __restrict__ out) {
  __shared__ int ids[64][4];
  const int tx = threadIdx.x & 63, ty = threadIdx.x >> 6;
  const int t0 = blockIdx.x * 64;
  ((int*)ids)[threadIdx.x] = final4[t0 * 4 + threadIdx.x];
  __syncthreads();
  const int d = blockIdx.y * 4 + ty;
  const float* row = R + (size_t)d * N_REF;
  const float sum = row[ids[tx][0]] + row[ids[tx][1]] + row[ids[tx][2]] + row[ids[tx][3]];
  out[(size_t)d * T_Q + t0 + tx] = 0.25f * sum;
}

#define FBM 64
#define FBN 256
#define FBK 16
#define FNL (N_REF / FBN)
__global__ __launch_bounds__(256)
void score_topk_kernel(const float* __restrict__ X, const float* __restrict__ R,
                       const float* __restrict__ r2,
                       float* __restrict__ pscore, int* __restrict__ pidx) {
  __shared__ float As[FBK][FBM];
  __shared__ float Bs[FBK][FBN];
  __shared__ float r2s[FBN];
  const int tid = threadIdx.x;
  const int tx = tid & 15, ty = tid >> 4;
  const int m0 = blockIdx.y * FBM;
  const int n0 = blockIdx.x * FBN;
  r2s[tid] = r2[n0 + tid];
  float acc[4][16];
#pragma unroll
  for (int i = 0; i < 4; ++i)
#pragma unroll
    for (int j = 0; j < 16; ++j) acc[i][j] = 0.f;
  for (int k0 = 0; k0 < DIM; k0 += FBK) {
    {
      const int k = tid >> 4, m4 = tid & 15;
      const float4 av = *(const float4*)&X[(size_t)(k0 + k) * T_Q + m0 + m4 * 4];
      *(float4*)&As[k][m4 * 4] = av;
    }
#pragma unroll
    for (int i = 0; i < 4; ++i) {
      const int idx4 = tid + i * 256;
      const int k = idx4 >> 6, n4 = idx4 & 63;
      const float4 bv = *(const float4*)&R[(size_t)(k0 + k) * N_REF + n0 + n4 * 4];
      *(float4*)&Bs[k][n4 * 4] = bv;
    }
    __syncthreads();
#pragma unroll
    for (int k = 0; k < FBK; ++k) {
      float av[4], bv[16];
      *(float4*)av = *(const float4*)&As[k][ty * 4];
#pragma unroll
      for (int c = 0; c < 4; ++c)
        *(float4*)&bv[c * 4] = *(const float4*)&Bs[k][tx * 4 + c * 64];
#pragma unroll
      for (int mi = 0; mi < 4; ++mi)
#pragma unroll
        for (int ni = 0; ni < 16; ++ni) acc[mi][ni] += av[mi] * bv[ni];
    }
    __syncthreads();
  }
#pragma unroll
  for (int mi = 0; mi < 4; ++mi) {
    float s[4]  = {1e30f, 1e30f, 1e30f, 1e30f};
    int   id[4] = {0x7fffffff, 0x7fffffff, 0x7fffffff, 0x7fffffff};
#pragma unroll
    for (int c = 0; c < 4; ++c)
#pragma unroll
      for (int j = 0; j < 4; ++j) {
        const int nl = tx * 4 + c * 64 + j;
        const float sc = r2s[nl] - 2.0f * acc[mi][c * 4 + j];
        insert4(s, id, sc, n0 + nl);
      }
#pragma unroll
    for (int mask = 1; mask < 16; mask <<= 1) {
      float os[4]; int oid[4];
#pragma unroll
      for (int j = 0; j < 4; ++j) {
        os[j]  = __shfl_xor(s[j], mask);
        oid[j] = __shfl_xor(id[j], mask);
      }
      merge_top4(s, id, os, oid);
    }
    if (tx == 0) {
      const int t = m0 + ty * 4 + mi;
      const int base = (t * FNL + (int)blockIdx.x) * 4;
#pragma unroll
      for (int j = 0; j < 4; ++j) { pscore[base + j] = s[j]; pidx[base + j] = id[j]; }
    }
  }
}

template <int NLISTS>
__global__ __launch_bounds__(64)
void select_kernel(const float* __restrict__ pscore, const int* __restrict__ pidx,
                   int* __restrict__ final4) {
  const int t = blockIdx.x, lane = threadIdx.x;
  constexpr int LPL = NLISTS / 64;
  float s[4]  = {1e30f, 1e30f, 1e30f, 1e30f};
  int   id[4] = {0x7fffffff, 0x7fffffff, 0x7fffffff, 0x7fffffff};
#pragma unroll
  for (int li = 0; li < LPL; ++li) {
    const int base = (t * NLISTS + lane * LPL + li) * 4;
    const float4 sv = *(const float4*)&pscore[base];
    const int4   iv = *(const int4*)&pidx[base];
    float os[4] = {sv.x, sv.y, sv.z, sv.w};
    int  oid[4] = {iv.x, iv.y, iv.z, iv.w};
    merge_top4(s, id, os, oid);
  }
#pragma unroll
  for (int mask = 1; mask < 64; mask <<= 1) {
    float os[4]; int oid[4];
#pragma unroll
    for (int j = 0; j < 4; ++j) {
      os[j]  = __shfl_xor(s[j], mask);
      oid[j] = __shfl_xor(id[j], mask);
    }
    merge_top4(s, id, os, oid);
  }
  if (lane == 0) {
    int4 o; o.x = id[0]; o.y = id[1]; o.z = id[2]; o.w = id[3];
    *(int4*)&final4[t * 4] = o;
  }
}

extern "C" void kernel_launch(void* const* d_in, const int* in_sizes, int n_in,
                              void* d_out, int out_size, void* d_ws, size_t ws_size,
                              hipStream_t stream) {
  const float* X = (const float*)d_in[0];   // [768][2048]
  const float* R = (const float*)d_in[1];   // [768][16384]
  float* out = (float*)d_out;               // [768][2048]

  const size_t szA2 = (size_t)T_Q * KP2 * sizeof(f16);        // 6,291,456
  const size_t szB2 = (size_t)N_REF * KP2 * sizeof(f16);      // 50,331,648
  const size_t szr2 = (size_t)N_REF * sizeof(float);          // 65,536
  const size_t szRP = (size_t)NDB * N_REF * sizeof(float);    // 786,432
  const size_t szPL = (size_t)T_Q * NL * 4 * sizeof(u64);     // 8,388,608
  const size_t need = szA2 + szB2 + szr2 + szRP + szPL +
                      (size_t)T_Q * 4 * sizeof(int);

  if (ws_size >= need) {
    char* w = (char*)d_ws;
    f16* A2 = (f16*)w;            w += szA2;
    f16* B2 = (f16*)w;            w += szB2;
    float* r2     = (float*)w;    w += szr2;
    float* r2p    = (float*)w;    w += szRP;
    u64*   plist  = (u64*)w;      w += szPL;
    int*   final4 = (int*)w;

    hipLaunchKernelGGL(tsplit_kernel, dim3(T_Q / 64, DIM / 64), dim3(256), 0, stream,
                       X, A2, T_Q);
    hipLaunchKernelGGL(tsplitR_kernel, dim3(N_REF / 64, DIM / 64), dim3(256), 0, stream,
                       R, B2, r2p);
    hipLaunchKernelGGL(r2sum_kernel, dim3(N_REF / 256), dim3(256), 0, stream, r2p, r2);
    hipLaunchKernelGGL(mfma128_topk_kernel, dim3((N_REF / 128) * (T_Q / 128)), dim3(256), 0,
                       stream, A2, B2, r2, plist);
    hipLaunchKernelGGL(selres_kernel, dim3(T_Q), dim3(64), 0, stream,
                       plist, A2, B2, r2, final4);
    hipLaunchKernelGGL(gatherB2_kernel, dim3(T_Q / 64, DIM / 128), dim3(256), 0, stream,
                       B2, final4, out);
  } else {
    // fallback: fp32 pipeline (~4.2 MB ws)
    char* w = (char*)d_ws;
    float* r2     = (float*)w;  w += szr2;
    float* pscore = (float*)w;  w += (size_t)T_Q * FNL * 4 * sizeof(float);
    int*   pidx   = (int*)w;    w += (size_t)T_Q * FNL * 4 * sizeof(int);
    int*   final4 = (int*)w;

    hipLaunchKernelGGL(r2_kernel, dim3(N_REF / 64), dim3(256), 0, stream, R, r2);
    hipLaunchKernelGGL(score_topk_kernel, dim3(N_REF / FBN, T_Q / FBM), dim3(256), 0, stream,
                       X, R, r2, pscore, pidx);
    hipLaunchKernelGGL((select_kernel<FNL>), dim3(T_Q), dim3(64), 0, stream,
                       pscore, pidx, final4);
    hipLaunchKernelGGL(gather_kernel, dim3(T_Q / 64, DIM / 4), dim3(256), 0, stream,
                       R, final4, out);
  }
}

// Round 15
// 144.364 us; speedup vs baseline: 1.1188x; 1.1188x over previous
//
#include <hip/hip_runtime.h>
#include <stdint.h>

#define T_Q   2048
#define N_REF 16384
#define DIM   768
#define KP2   1536        // packed K cols: [hi | lo]
#define NT    24          // K = 768 = 24 tiles of 32 (hi limb only)
#define NL    128         // partial top-4 lists per query (128-col block stripes)
#define NDB   (DIM / 64)  // 12 d-blocks for partial r2

using f16   = _Float16;
using f16x4 = __attribute__((ext_vector_type(4))) _Float16;
using f16x8 = __attribute__((ext_vector_type(8))) _Float16;
using f32x4 = __attribute__((ext_vector_type(4))) float;
typedef unsigned long long u64;

// ---------- exact-path lexicographic top-4 (float score, int idx) ----------
__device__ __forceinline__ bool lex_less(float sa, int ia, float sb, int ib) {
  return (sa < sb) || (sa == sb && ia < ib);
}
#define CE_PAIR(s0, i0, s1, i1)                                        \
  { if (lex_less(s1, i1, s0, i0)) { float _ts = s0; s0 = s1; s1 = _ts; \
                                    int _ti = i0; i0 = i1; i1 = _ti; } }
#define PICKMIN(as, ai, bs, bi, rs, ri)                   \
  { if (lex_less(bs, bi, as, ai)) { rs = bs; ri = bi; }   \
    else                          { rs = as; ri = ai; } }

__device__ __forceinline__ void insert4(float s[4], int id[4], float sc, int n) {
  if (lex_less(sc, n, s[3], id[3])) {
    s[3] = sc; id[3] = n;
    CE_PAIR(s[2], id[2], s[3], id[3]);
    CE_PAIR(s[1], id[1], s[2], id[2]);
    CE_PAIR(s[0], id[0], s[1], id[1]);
  }
}
__device__ __forceinline__ void merge_top4(float s[4], int id[4],
                                           const float os[4], const int oid[4]) {
  float l0, l1, l2, l3; int j0, j1, j2, j3;
  PICKMIN(s[0], id[0], os[3], oid[3], l0, j0);
  PICKMIN(s[1], id[1], os[2], oid[2], l1, j1);
  PICKMIN(s[2], id[2], os[1], oid[1], l2, j2);
  PICKMIN(s[3], id[3], os[0], oid[0], l3, j3);
  CE_PAIR(l0, j0, l2, j2);
  CE_PAIR(l1, j1, l3, j3);
  CE_PAIR(l0, j0, l1, j1);
  CE_PAIR(l2, j2, l3, j3);
  s[0] = l0; s[1] = l1; s[2] = l2; s[3] = l3;
  id[0] = j0; id[1] = j1; id[2] = j2; id[3] = j3;
}

// ---------- packed-u64 ranking: (sortable_score32 << 32) | col ----------
__device__ __forceinline__ uint32_t fsort32(float f) {
  uint32_t u = __float_as_uint(f);
  return ((int)u < 0) ? ~u : (u | 0x80000000u);
}
__device__ __forceinline__ void ins4u(u64 s[4], u64 c) {
  if (c < s[3]) {
    s[3] = c;
    if (s[3] < s[2]) { u64 t = s[2]; s[2] = s[3]; s[3] = t; }
    if (s[2] < s[1]) { u64 t = s[1]; s[1] = s[2]; s[2] = t; }
    if (s[1] < s[0]) { u64 t = s[0]; s[0] = s[1]; s[1] = t; }
  }
}
#define CEU(a, b) { u64 _mn = (a) < (b) ? (a) : (b); \
                    u64 _mx = (a) < (b) ? (b) : (a); (a) = _mn; (b) = _mx; }
__device__ __forceinline__ void merge4u(u64 s[4], const u64 o[4]) {
  u64 l0 = s[0] < o[3] ? s[0] : o[3];
  u64 l1 = s[1] < o[2] ? s[1] : o[2];
  u64 l2 = s[2] < o[1] ? s[2] : o[1];
  u64 l3 = s[3] < o[0] ? s[3] : o[0];
  CEU(l0, l2); CEU(l1, l3); CEU(l0, l1); CEU(l2, l3);
  s[0] = l0; s[1] = l1; s[2] = l2; s[3] = l3;
}
__device__ __forceinline__ void merge8u(u64 s[8], const u64 o[8]) {
  u64 l0 = s[0] < o[7] ? s[0] : o[7];
  u64 l1 = s[1] < o[6] ? s[1] : o[6];
  u64 l2 = s[2] < o[5] ? s[2] : o[5];
  u64 l3 = s[3] < o[4] ? s[3] : o[4];
  u64 l4 = s[4] < o[3] ? s[4] : o[3];
  u64 l5 = s[5] < o[2] ? s[5] : o[2];
  u64 l6 = s[6] < o[1] ? s[6] : o[1];
  u64 l7 = s[7] < o[0] ? s[7] : o[0];
  CEU(l0, l4); CEU(l1, l5); CEU(l2, l6); CEU(l3, l7);
  CEU(l0, l2); CEU(l1, l3); CEU(l4, l6); CEU(l5, l7);
  CEU(l0, l1); CEU(l2, l3); CEU(l4, l5); CEU(l6, l7);
  s[0]=l0; s[1]=l1; s[2]=l2; s[3]=l3; s[4]=l4; s[5]=l5; s[6]=l6; s[7]=l7;
}

__device__ __forceinline__ void gl_lds16(const void* g, void* l) {
  __builtin_amdgcn_global_load_lds((const __attribute__((address_space(1))) uint32_t*)g,
                                   (__attribute__((address_space(3))) uint32_t*)l, 16, 0, 0);
}

// ---------- fused transpose + f16 hi/lo split for X AND R (+ partial r2) ----------
// grid.x = T_Q/64 + N_REF/64 = 288; grid.y = NDB. Block-uniform branch.
__global__ __launch_bounds__(256)
void tsplit2_kernel(const float* __restrict__ X, const float* __restrict__ R,
                    f16* __restrict__ A2, f16* __restrict__ B2,
                    float* __restrict__ r2p) {
  __shared__ f16 lh[64][66], ll[64][66];
  const int bxg = (int)blockIdx.x;
  const bool isX = bxg < (T_Q / 64);
  const float* in = isX ? X : R;
  const int W = isX ? T_Q : N_REF;
  f16* out = isX ? A2 : B2;
  const int c0 = (isX ? bxg : bxg - T_Q / 64) * 64;
  const int d0 = blockIdx.y * 64;
  const int q = threadIdx.x & 15, p = threadIdx.x >> 4;
  float a0 = 0.f, a1 = 0.f, a2 = 0.f, a3 = 0.f;
#pragma unroll
  for (int i = 0; i < 4; ++i) {
    const int dl = p + i * 16;
    const float4 v = *(const float4*)&in[(size_t)(d0 + dl) * W + c0 + q * 4];
    const f16 h0 = (f16)v.x, h1 = (f16)v.y, h2 = (f16)v.z, h3 = (f16)v.w;
    lh[q * 4 + 0][dl] = h0; ll[q * 4 + 0][dl] = (f16)(v.x - (float)h0);
    lh[q * 4 + 1][dl] = h1; ll[q * 4 + 1][dl] = (f16)(v.y - (float)h1);
    lh[q * 4 + 2][dl] = h2; ll[q * 4 + 2][dl] = (f16)(v.z - (float)h2);
    lh[q * 4 + 3][dl] = h3; ll[q * 4 + 3][dl] = (f16)(v.w - (float)h3);
    a0 = fmaf(v.x, v.x, a0); a1 = fmaf(v.y, v.y, a1);
    a2 = fmaf(v.z, v.z, a2); a3 = fmaf(v.w, v.w, a3);
  }
  __syncthreads();
  const int rl = threadIdx.x >> 2, seg = threadIdx.x & 3;
  f16* rowo = out + (size_t)(c0 + rl) * KP2 + d0;
#pragma unroll
  for (int j = 0; j < 4; ++j) {
    const int dd = seg * 16 + j * 4;
    f16x4 vh = *(const f16x4*)&lh[rl][dd];
    f16x4 vl = *(const f16x4*)&ll[rl][dd];
    *(f16x4*)&rowo[dd] = vh;
    *(f16x4*)&rowo[768 + dd] = vl;
  }
  if (!isX) {
    // partial r2 over this block's 64 d's (deterministic fixed-order reduce)
    __syncthreads();
    float* sq = (float*)lh;   // 16 x 64 f32 = 4 KB
    sq[p * 64 + q * 4 + 0] = a0;
    sq[p * 64 + q * 4 + 1] = a1;
    sq[p * 64 + q * 4 + 2] = a2;
    sq[p * 64 + q * 4 + 3] = a3;
    __syncthreads();
    if (threadIdx.x < 64) {
      float s = 0.f;
#pragma unroll
      for (int pp = 0; pp < 16; ++pp) s += sq[pp * 64 + threadIdx.x];
      r2p[(size_t)blockIdx.y * N_REF + c0 + threadIdx.x] = s;
    }
  }
}

// ---------- m97-geometry 128x128 f16-hi MFMA GEMM + fused approx top-4 ----------
// K-loop r11-verbatim. Epilogue: inline r2 from 12 partials (fixed order,
// bit-identical to old r2sum), u64 lists, cross-wn merge -> NL=128.
__global__ __launch_bounds__(256, 2)
void mfma128_topk_kernel(const f16* __restrict__ A2, const f16* __restrict__ B2,
                         const float* __restrict__ r2p, u64* __restrict__ plist) {
  __shared__ __align__(16) char smem[33792];
  const int tid  = threadIdx.x;
  const int lane = tid & 63, wid = tid >> 6;
  const int wm = wid >> 1, wn = wid & 1;
  const int ln15 = lane & 15, g4 = lane >> 4;

  const int flat = (int)blockIdx.x;
  const int jj = flat >> 3;
  const int bx = (flat & 7) * 16 + (jj & 15);  // 0..127
  const int by = jj >> 4;                      // 0..15
  const int m0 = by * 128, n0 = bx * 128;

  const int s0 = tid, s1 = tid + 256;
  const int r0 = s0 >> 2, r1 = s1 >> 2;
  const int c0b = (((s0 & 3) ^ ((s0 >> 3) & 3)) << 4);
  const int c1b = (((s1 & 3) ^ ((s1 >> 3) & 3)) << 4);
  const char* gA0 = (const char*)(A2 + (size_t)(m0 + r0) * KP2) + c0b;
  const char* gA1 = (const char*)(A2 + (size_t)(m0 + r1) * KP2) + c1b;
  const char* gB0 = (const char*)(B2 + (size_t)(n0 + r0) * KP2) + c0b;
  const char* gB1 = (const char*)(B2 + (size_t)(n0 + r1) * KP2) + c1b;
  const int l0 = s0 * 16, l1 = s1 * 16;

#define STAGE_A(bufo, kbyte)                                     \
  { gl_lds16(gA0 + (kbyte), smem + (bufo) + l0);                 \
    gl_lds16(gA1 + (kbyte), smem + (bufo) + l1); }
#define STAGE_B(bufo, kbyte)                                     \
  { gl_lds16(gB0 + (kbyte), smem + (bufo) + 8192 + l0);          \
    gl_lds16(gB1 + (kbyte), smem + (bufo) + 8192 + l1); }

  const int cswz = ((g4 ^ ((ln15 >> 1) & 3)) << 4);
  int offA[4], offB[4];
#pragma unroll
  for (int mi = 0; mi < 4; ++mi) offA[mi] = (wm * 64 + mi * 16 + ln15) * 64 + cswz;
#pragma unroll
  for (int ni = 0; ni < 4; ++ni) offB[ni] = 8192 + (wn * 64 + ni * 16 + ln15) * 64 + cswz;

  f32x4 acc[4][4] = {};

  STAGE_A(0, 0);
  STAGE_B(0, 0);

  for (int kt = 0; kt < NT; ++kt) {
    const int dbuf = (kt & 1) << 14;
    const int sdb  = ((kt + 1) & 1) << 14;
    const int ktn = (kt + 1 < NT) ? kt + 1 : NT - 1;

    STAGE_A(sdb, ktn * 64);
    STAGE_B(sdb, ktn * 64);
    asm volatile("s_waitcnt vmcnt(4)" ::: "memory");
    asm volatile("s_barrier" ::: "memory");

    f16x8 a[4], b[4];
    a[0] = *(const f16x8*)(smem + dbuf + offA[0]);
    b[0] = *(const f16x8*)(smem + dbuf + offB[0]);
    a[1] = *(const f16x8*)(smem + dbuf + offA[1]);
    b[1] = *(const f16x8*)(smem + dbuf + offB[1]);
    a[2] = *(const f16x8*)(smem + dbuf + offA[2]);
    b[2] = *(const f16x8*)(smem + dbuf + offB[2]);
    a[3] = *(const f16x8*)(smem + dbuf + offA[3]);
    b[3] = *(const f16x8*)(smem + dbuf + offB[3]);

    __builtin_amdgcn_s_setprio(1);
#pragma unroll
    for (int mi = 0; mi < 4; ++mi)
#pragma unroll
      for (int ni = 0; ni < 4; ++ni)
        acc[mi][ni] = __builtin_amdgcn_mfma_f32_16x16x32_f16(a[mi], b[ni], acc[mi][ni], 0, 0, 0);
    __builtin_amdgcn_s_setprio(0);
    asm volatile("s_barrier" ::: "memory");
  }

  asm volatile("s_waitcnt vmcnt(0)" ::: "memory");
  __syncthreads();

  // ---- epilogue: inline r2 partial sum (fixed order), scatter sortable-u32 ----
  float rv[4];
#pragma unroll
  for (int ni = 0; ni < 4; ++ni) {
    const int col = n0 + wn * 64 + ni * 16 + ln15;
    float s = 0.f;
#pragma unroll
    for (int k = 0; k < NDB; ++k) s += r2p[(size_t)k * N_REF + col];
    rv[ni] = s;
  }
  uint32_t* swu = (uint32_t*)smem + wid * 2112;   // [32][66] u32, wave-private
  const int rr = lane >> 1, hh = lane & 1;
  u64 keep[2][4];
#pragma unroll
  for (int P = 0; P < 2; ++P) {
#pragma unroll
    for (int mh = 0; mh < 2; ++mh)
#pragma unroll
      for (int ni = 0; ni < 4; ++ni)
#pragma unroll
        for (int r = 0; r < 4; ++r) {
          const int row_l = mh * 16 + g4 * 4 + r;   // C/D: col=lane&15, row=(lane>>4)*4+reg
          swu[row_l * 66 + ni * 16 + ln15] = fsort32(rv[ni] - 2.0f * acc[2 * P + mh][ni][r]);
        }
    asm volatile("s_waitcnt lgkmcnt(0)" ::: "memory");
    __builtin_amdgcn_sched_barrier(0);
    u64 s[4] = {~0ull, ~0ull, ~0ull, ~0ull};
    const uint32_t* rowp = swu + rr * 66 + hh * 32;
    const uint32_t cb = (uint32_t)(n0 + wn * 64 + hh * 32);
#pragma unroll
    for (int j = 0; j < 16; ++j) {
      const uint2 v = *(const uint2*)(rowp + j * 2);
      ins4u(s, ((u64)v.x << 32) | (cb + j * 2));
      ins4u(s, ((u64)v.y << 32) | (cb + j * 2 + 1));
    }
    u64 os[4];
#pragma unroll
    for (int j = 0; j < 4; ++j) os[j] = __shfl_xor((u64)s[j], 1);
    merge4u(s, os);
#pragma unroll
    for (int j = 0; j < 4; ++j) keep[P][j] = s[j];
    asm volatile("s_waitcnt lgkmcnt(0)" ::: "memory");
  }

  // ---- cross-wn merge: one 4-list per query row per block (NL = 128) ----
  __syncthreads();
  u64* lbuf = (u64*)smem;               // [128 rows][4] u64 = 4 KB
  if (wn == 1 && hh == 0) {
#pragma unroll
    for (int P = 0; P < 2; ++P) {
      const int lrow = wm * 64 + P * 32 + rr;
#pragma unroll
      for (int j = 0; j < 4; ++j) lbuf[lrow * 4 + j] = keep[P][j];
    }
  }
  __syncthreads();
  if (wn == 0 && hh == 0) {
#pragma unroll
    for (int P = 0; P < 2; ++P) {
      const int lrow = wm * 64 + P * 32 + rr;
      u64 o[4];
#pragma unroll
      for (int j = 0; j < 4; ++j) o[j] = lbuf[lrow * 4 + j];
      merge4u(keep[P], o);
      u64* dst = plist + ((size_t)(m0 + lrow) * NL + bx) * 4;
#pragma unroll
      for (int j = 0; j < 4; ++j) dst[j] = keep[P][j];
    }
  }
#undef STAGE_A
#undef STAGE_B
}

// ---------- fused select+rescore: 8 waves, wave w rescores candidate w ----------
__global__ __launch_bounds__(512)
void selres_kernel(const u64* __restrict__ plist,
                   const f16* __restrict__ A2, const f16* __restrict__ B2,
                   const float* __restrict__ r2p, int* __restrict__ final4) {
  const int t = blockIdx.x;
  const int lane = threadIdx.x & 63, wid = threadIdx.x >> 6;
  __shared__ int cids[8];
  __shared__ float scs[8];

  if (wid == 0) {
    u64 s[8];
#pragma unroll
    for (int j = 0; j < 8; ++j) s[j] = ~0ull;
#pragma unroll
    for (int li = 0; li < 2; ++li) {
      const u64* src = plist + ((size_t)t * NL + lane * 2 + li) * 4;
      u64 o[8] = {src[0], src[1], src[2], src[3], ~0ull, ~0ull, ~0ull, ~0ull};
      merge8u(s, o);
    }
#pragma unroll
    for (int mask = 1; mask < 64; mask <<= 1) {
      u64 o[8];
#pragma unroll
      for (int j = 0; j < 8; ++j) o[j] = __shfl_xor((u64)s[j], mask);
      merge8u(s, o);
    }
    if (lane == 0) {
#pragma unroll
      for (int j = 0; j < 8; ++j) cids[j] = (int)(uint32_t)s[j];
    }
  }
  __syncthreads();

  const int cid = cids[wid];
  const f16* xrow = A2 + (size_t)t * KP2;
  const f16* rrow = B2 + (size_t)cid * KP2;
  float acc = 0.f;
#pragma unroll
  for (int k = 0; k < 12; ++k) {
    const float xhv = (float)xrow[lane + 64 * k];
    const float xlv = (float)xrow[768 + lane + 64 * k];
    const float rh = (float)rrow[lane + 64 * k];
    const float rl = (float)rrow[768 + lane + 64 * k];
    acc = fmaf(xhv, rh, acc);
    acc = fmaf(xhv, rl, acc);
    acc = fmaf(xlv, rh, acc);
  }
#pragma unroll
  for (int m = 1; m < 64; m <<= 1) acc += __shfl_xor(acc, m);
  float r2v = 0.f;
#pragma unroll
  for (int k = 0; k < NDB; ++k) r2v += r2p[(size_t)k * N_REF + cid];
  if (lane == 0) scs[wid] = r2v - 2.0f * acc;
  __syncthreads();

  if (threadIdx.x == 0) {
    float s4[4] = {1e30f, 1e30f, 1e30f, 1e30f};
    int   i4[4] = {0x7fffffff, 0x7fffffff, 0x7fffffff, 0x7fffffff};
#pragma unroll
    for (int j = 0; j < 8; ++j) insert4(s4, i4, scs[j], cids[j]);
    int4 o; o.x = i4[0]; o.y = i4[1]; o.z = i4[2]; o.w = i4[3];
    *(int4*)&final4[t * 4] = o;
  }
}

// ---------- gather from B2 rows (coalesced) + LDS transpose -> out [d][T] ----------
__global__ __launch_bounds__(256)
void gatherB2_kernel(const f16* __restrict__ B2, const int* __restrict__ final4,
                     float* __restrict__ out) {
  __shared__ int ids[64][4];
  __shared__ float tr[64][129];
  const int tid = threadIdx.x;
  const int t0 = blockIdx.x * 64;
  const int d0 = blockIdx.y * 128;
  ((int*)ids)[tid] = final4[t0 * 4 + tid];
  __syncthreads();

  const int q = tid >> 2, dp = tid & 3;
  float a[32];
#pragma unroll
  for (int k = 0; k < 32; ++k) a[k] = 0.f;
#pragma unroll
  for (int j = 0; j < 4; ++j) {
    const f16* row = B2 + (size_t)ids[q][j] * KP2 + d0 + dp * 32;
#pragma unroll
    for (int v = 0; v < 4; ++v) {
      const f16x8 h = *(const f16x8*)(row + v * 8);
      const f16x8 l = *(const f16x8*)(row + 768 + v * 8);
#pragma unroll
      for (int e = 0; e < 8; ++e) a[v * 8 + e] += (float)h[e] + (float)l[e];
    }
  }
#pragma unroll
  for (int k = 0; k < 32; ++k) tr[q][dp * 32 + k] = 0.25f * a[k];
  __syncthreads();

  const int dd = tid >> 1, hf = tid & 1;
  float* orow = out + (size_t)(d0 + dd) * T_Q + t0 + hf * 32;
#pragma unroll
  for (int k = 0; k < 8; ++k) {
    float4 v4;
    v4.x = tr[hf * 32 + k * 4 + 0][dd];
    v4.y = tr[hf * 32 + k * 4 + 1][dd];
    v4.z = tr[hf * 32 + k * 4 + 2][dd];
    v4.w = tr[hf * 32 + k * 4 + 3][dd];
    *(float4*)(orow + k * 4) = v4;
  }
}

// ---------- fallback fp32 pipeline (round-1, known correct) ----------
__global__ __launch_bounds__(256)
void r2_kernel(const float* __restrict__ R, float* __restrict__ r2) {
  __shared__ float red[256];
  const int lane = threadIdx.x & 63;
  const int dg   = threadIdx.x >> 6;
  const int n    = blockIdx.x * 64 + lane;
  float acc = 0.f;
  const int d0 = dg * (DIM / 4), d1 = d0 + (DIM / 4);
  for (int d = d0; d < d1; ++d) {
    float v = R[(size_t)d * N_REF + n];
    acc += v * v;
  }
  red[threadIdx.x] = acc;
  __syncthreads();
  if (threadIdx.x < 64)
    r2[n] = red[lane] + red[lane + 64] + red[lane + 128] + red[lane + 192];
}

__global__ __launch_bounds__(256)
void gather_kernel(const float* __restrict__ R, const int* __restrict__ final4,
                   float* __restrict__ out) {
  __shared__ int ids[64][4];
  const int tx = threadIdx.x & 63, ty = threadIdx.x >> 6;
  const int t0 = blockIdx.x * 64;
  ((int*)ids)[threadIdx.x] = final4[t0 * 4 + threadIdx.x];
  __syncthreads();
  const int d = blockIdx.y * 4 + ty;
  const float* row = R + (size_t)d * N_REF;
  const float sum = row[ids[tx][0]] + row[ids[tx][1]] + row[ids[tx][2]] + row[ids[tx][3]];
  out[(size_t)d * T_Q + t0 + tx] = 0.25f * sum;
}

#define FBM 64
#define FBN 256
#define FBK 16
#define FNL (N_REF / FBN)
__global__ __launch_bounds__(256)
void score_topk_kernel(const float* __restrict__ X, const float* __restrict__ R,
                       const float* __restrict__ r2,
                       float* __restrict__ pscore, int* __restrict__ pidx) {
  __shared__ float As[FBK][FBM];
  __shared__ float Bs[FBK][FBN];
  __shared__ float r2s[FBN];
  const int tid = threadIdx.x;
  const int tx = tid & 15, ty = tid >> 4;
  const int m0 = blockIdx.y * FBM;
  const int n0 = blockIdx.x * FBN;
  r2s[tid] = r2[n0 + tid];
  float acc[4][16];
#pragma unroll
  for (int i = 0; i < 4; ++i)
#pragma unroll
    for (int j = 0; j < 16; ++j) acc[i][j] = 0.f;
  for (int k0 = 0; k0 < DIM; k0 += FBK) {
    {
      const int k = tid >> 4, m4 = tid & 15;
      const float4 av = *(const float4*)&X[(size_t)(k0 + k) * T_Q + m0 + m4 * 4];
      *(float4*)&As[k][m4 * 4] = av;
    }
#pragma unroll
    for (int i = 0; i < 4; ++i) {
      const int idx4 = tid + i * 256;
      const int k = idx4 >> 6, n4 = idx4 & 63;
      const float4 bv = *(const float4*)&R[(size_t)(k0 + k) * N_REF + n0 + n4 * 4];
      *(float4*)&Bs[k][n4 * 4] = bv;
    }
    __syncthreads();
#pragma unroll
    for (int k = 0; k < FBK; ++k) {
      float av[4], bv[16];
      *(float4*)av = *(const float4*)&As[k][ty * 4];
#pragma unroll
      for (int c = 0; c < 4; ++c)
        *(float4*)&bv[c * 4] = *(const float4*)&Bs[k][tx * 4 + c * 64];
#pragma unroll
      for (int mi = 0; mi < 4; ++mi)
#pragma unroll
        for (int ni = 0; ni < 16; ++ni) acc[mi][ni] += av[mi] * bv[ni];
    }
    __syncthreads();
  }
#pragma unroll
  for (int mi = 0; mi < 4; ++mi) {
    float s[4]  = {1e30f, 1e30f, 1e30f, 1e30f};
    int   id[4] = {0x7fffffff, 0x7fffffff, 0x7fffffff, 0x7fffffff};
#pragma unroll
    for (int c = 0; c < 4; ++c)
#pragma unroll
      for (int j = 0; j < 4; ++j) {
        const int nl = tx * 4 + c * 64 + j;
        const float sc = r2s[nl] - 2.0f * acc[mi][c * 4 + j];
        insert4(s, id, sc, n0 + nl);
      }
#pragma unroll
    for (int mask = 1; mask < 16; mask <<= 1) {
      float os[4]; int oid[4];
#pragma unroll
      for (int j = 0; j < 4; ++j) {
        os[j]  = __shfl_xor(s[j], mask);
        oid[j] = __shfl_xor(id[j], mask);
      }
      merge_top4(s, id, os, oid);
    }
    if (tx == 0) {
      const int t = m0 + ty * 4 + mi;
      const int base = (t * FNL + (int)blockIdx.x) * 4;
#pragma unroll
      for (int j = 0; j < 4; ++j) { pscore[base + j] = s[j]; pidx[base + j] = id[j]; }
    }
  }
}

template <int NLISTS>
__global__ __launch_bounds__(64)
void select_kernel(const float* __restrict__ pscore, const int* __restrict__ pidx,
                   int* __restrict__ final4) {
  const int t = blockIdx.x, lane = threadIdx.x;
  constexpr int LPL = NLISTS / 64;
  float s[4]  = {1e30f, 1e30f, 1e30f, 1e30f};
  int   id[4] = {0x7fffffff, 0x7fffffff, 0x7fffffff, 0x7fffffff};
#pragma unroll
  for (int li = 0; li < LPL; ++li) {
    const int base = (t * NLISTS + lane * LPL + li) * 4;
    const float4 sv = *(const float4*)&pscore[base];
    const int4   iv = *(const int4*)&pidx[base];
    float os[4] = {sv.x, sv.y, sv.z, sv.w};
    int  oid[4] = {iv.x, iv.y, iv.z, iv.w};
    merge_top4(s, id, os, oid);
  }
#pragma unroll
  for (int mask = 1; mask < 64; mask <<= 1) {
    float os[4]; int oid[4];
#pragma unroll
    for (int j = 0; j < 4; ++j) {
      os[j]  = __shfl_xor(s[j], mask);
      oid[j] = __shfl_xor(id[j], mask);
    }
    merge_top4(s, id, os, oid);
  }
  if (lane == 0) {
    int4 o; o.x = id[0]; o.y = id[1]; o.z = id[2]; o.w = id[3];
    *(int4*)&final4[t * 4] = o;
  }
}

extern "C" void kernel_launch(void* const* d_in, const int* in_sizes, int n_in,
                              void* d_out, int out_size, void* d_ws, size_t ws_size,
                              hipStream_t stream) {
  const float* X = (const float*)d_in[0];   // [768][2048]
  const float* R = (const float*)d_in[1];   // [768][16384]
  float* out = (float*)d_out;               // [768][2048]

  const size_t szA2 = (size_t)T_Q * KP2 * sizeof(f16);        // 6,291,456
  const size_t szB2 = (size_t)N_REF * KP2 * sizeof(f16);      // 50,331,648
  const size_t szRP = (size_t)NDB * N_REF * sizeof(float);    // 786,432
  const size_t szPL = (size_t)T_Q * NL * 4 * sizeof(u64);     // 8,388,608
  const size_t need = szA2 + szB2 + szRP + szPL + (size_t)T_Q * 4 * sizeof(int);

  if (ws_size >= need) {
    char* w = (char*)d_ws;
    f16* A2 = (f16*)w;            w += szA2;
    f16* B2 = (f16*)w;            w += szB2;
    float* r2p    = (float*)w;    w += szRP;
    u64*   plist  = (u64*)w;      w += szPL;
    int*   final4 = (int*)w;

    hipLaunchKernelGGL(tsplit2_kernel, dim3(T_Q / 64 + N_REF / 64, NDB), dim3(256), 0,
                       stream, X, R, A2, B2, r2p);
    hipLaunchKernelGGL(mfma128_topk_kernel, dim3((N_REF / 128) * (T_Q / 128)), dim3(256), 0,
                       stream, A2, B2, r2p, plist);
    hipLaunchKernelGGL(selres_kernel, dim3(T_Q), dim3(512), 0, stream,
                       plist, A2, B2, r2p, final4);
    hipLaunchKernelGGL(gatherB2_kernel, dim3(T_Q / 64, DIM / 128), dim3(256), 0, stream,
                       B2, final4, out);
  } else {
    // fallback: fp32 pipeline (~4.2 MB ws)
    char* w = (char*)d_ws;
    float* r2     = (float*)w;  w += (size_t)N_REF * sizeof(float);
    float* pscore = (float*)w;  w += (size_t)T_Q * FNL * 4 * sizeof(float);
    int*   pidx   = (int*)w;    w += (size_t)T_Q * FNL * 4 * sizeof(int);
    int*   final4 = (int*)w;

    hipLaunchKernelGGL(r2_kernel, dim3(N_REF / 64), dim3(256), 0, stream, R, r2);
    hipLaunchKernelGGL(score_topk_kernel, dim3(N_REF / FBN, T_Q / FBM), dim3(256), 0, stream,
                       X, R, r2, pscore, pidx);
    hipLaunchKernelGGL((select_kernel<FNL>), dim3(T_Q), dim3(64), 0, stream,
                       pscore, pidx, final4);
    hipLaunchKernelGGL(gather_kernel, dim3(T_Q / 64, DIM / 4), dim3(256), 0, stream,
                       R, final4, out);
  }
}

// Round 16
// 136.250 us; speedup vs baseline: 1.1854x; 1.0595x over previous
//
#include <hip/hip_runtime.h>
#include <stdint.h>

#define T_Q   2048
#define N_REF 16384
#define DIM   768
#define KP2   1536        // packed K cols: [hi | lo]
#define NT    24          // K = 768 = 24 tiles of 32 (hi limb only)
#define NL    128         // partial top-4 lists per query (128-col block stripes)
#define NDB   (DIM / 64)  // 12 d-blocks for partial r2

using f16   = _Float16;
using f16x4 = __attribute__((ext_vector_type(4))) _Float16;
using f16x8 = __attribute__((ext_vector_type(8))) _Float16;
using f32x4 = __attribute__((ext_vector_type(4))) float;
typedef unsigned long long u64;

// ---------- exact-path lexicographic top-4 (float score, int idx) ----------
__device__ __forceinline__ bool lex_less(float sa, int ia, float sb, int ib) {
  return (sa < sb) || (sa == sb && ia < ib);
}
#define CE_PAIR(s0, i0, s1, i1)                                        \
  { if (lex_less(s1, i1, s0, i0)) { float _ts = s0; s0 = s1; s1 = _ts; \
                                    int _ti = i0; i0 = i1; i1 = _ti; } }
#define PICKMIN(as, ai, bs, bi, rs, ri)                   \
  { if (lex_less(bs, bi, as, ai)) { rs = bs; ri = bi; }   \
    else                          { rs = as; ri = ai; } }

__device__ __forceinline__ void insert4(float s[4], int id[4], float sc, int n) {
  if (lex_less(sc, n, s[3], id[3])) {
    s[3] = sc; id[3] = n;
    CE_PAIR(s[2], id[2], s[3], id[3]);
    CE_PAIR(s[1], id[1], s[2], id[2]);
    CE_PAIR(s[0], id[0], s[1], id[1]);
  }
}
__device__ __forceinline__ void merge_top4(float s[4], int id[4],
                                           const float os[4], const int oid[4]) {
  float l0, l1, l2, l3; int j0, j1, j2, j3;
  PICKMIN(s[0], id[0], os[3], oid[3], l0, j0);
  PICKMIN(s[1], id[1], os[2], oid[2], l1, j1);
  PICKMIN(s[2], id[2], os[1], oid[1], l2, j2);
  PICKMIN(s[3], id[3], os[0], oid[0], l3, j3);
  CE_PAIR(l0, j0, l2, j2);
  CE_PAIR(l1, j1, l3, j3);
  CE_PAIR(l0, j0, l1, j1);
  CE_PAIR(l2, j2, l3, j3);
  s[0] = l0; s[1] = l1; s[2] = l2; s[3] = l3;
  id[0] = j0; id[1] = j1; id[2] = j2; id[3] = j3;
}

// ---------- packed-u64 ranking: (sortable_score32 << 32) | col ----------
__device__ __forceinline__ uint32_t fsort32(float f) {
  uint32_t u = __float_as_uint(f);
  return ((int)u < 0) ? ~u : (u | 0x80000000u);
}
__device__ __forceinline__ void ins4u(u64 s[4], u64 c) {
  if (c < s[3]) {
    s[3] = c;
    if (s[3] < s[2]) { u64 t = s[2]; s[2] = s[3]; s[3] = t; }
    if (s[2] < s[1]) { u64 t = s[1]; s[1] = s[2]; s[2] = t; }
    if (s[1] < s[0]) { u64 t = s[0]; s[0] = s[1]; s[1] = t; }
  }
}
#define CEU(a, b) { u64 _mn = (a) < (b) ? (a) : (b); \
                    u64 _mx = (a) < (b) ? (b) : (a); (a) = _mn; (b) = _mx; }
__device__ __forceinline__ void merge4u(u64 s[4], const u64 o[4]) {
  u64 l0 = s[0] < o[3] ? s[0] : o[3];
  u64 l1 = s[1] < o[2] ? s[1] : o[2];
  u64 l2 = s[2] < o[1] ? s[2] : o[1];
  u64 l3 = s[3] < o[0] ? s[3] : o[0];
  CEU(l0, l2); CEU(l1, l3); CEU(l0, l1); CEU(l2, l3);
  s[0] = l0; s[1] = l1; s[2] = l2; s[3] = l3;
}
__device__ __forceinline__ void merge8u(u64 s[8], const u64 o[8]) {
  u64 l0 = s[0] < o[7] ? s[0] : o[7];
  u64 l1 = s[1] < o[6] ? s[1] : o[6];
  u64 l2 = s[2] < o[5] ? s[2] : o[5];
  u64 l3 = s[3] < o[4] ? s[3] : o[4];
  u64 l4 = s[4] < o[3] ? s[4] : o[3];
  u64 l5 = s[5] < o[2] ? s[5] : o[2];
  u64 l6 = s[6] < o[1] ? s[6] : o[1];
  u64 l7 = s[7] < o[0] ? s[7] : o[0];
  CEU(l0, l4); CEU(l1, l5); CEU(l2, l6); CEU(l3, l7);
  CEU(l0, l2); CEU(l1, l3); CEU(l4, l6); CEU(l5, l7);
  CEU(l0, l1); CEU(l2, l3); CEU(l4, l5); CEU(l6, l7);
  s[0]=l0; s[1]=l1; s[2]=l2; s[3]=l3; s[4]=l4; s[5]=l5; s[6]=l6; s[7]=l7;
}

__device__ __forceinline__ void gl_lds16(const void* g, void* l) {
  __builtin_amdgcn_global_load_lds((const __attribute__((address_space(1))) uint32_t*)g,
                                   (__attribute__((address_space(3))) uint32_t*)l, 16, 0, 0);
}

// ---------- fused transpose + f16 hi/lo split for X AND R (+ partial r2) ----------
__global__ __launch_bounds__(256)
void tsplit2_kernel(const float* __restrict__ X, const float* __restrict__ R,
                    f16* __restrict__ A2, f16* __restrict__ B2,
                    float* __restrict__ r2p) {
  __shared__ f16 lh[64][66], ll[64][66];
  const int bxg = (int)blockIdx.x;
  const bool isX = bxg < (T_Q / 64);
  const float* in = isX ? X : R;
  const int W = isX ? T_Q : N_REF;
  f16* out = isX ? A2 : B2;
  const int c0 = (isX ? bxg : bxg - T_Q / 64) * 64;
  const int d0 = blockIdx.y * 64;
  const int q = threadIdx.x & 15, p = threadIdx.x >> 4;
  float a0 = 0.f, a1 = 0.f, a2 = 0.f, a3 = 0.f;
#pragma unroll
  for (int i = 0; i < 4; ++i) {
    const int dl = p + i * 16;
    const float4 v = *(const float4*)&in[(size_t)(d0 + dl) * W + c0 + q * 4];
    const f16 h0 = (f16)v.x, h1 = (f16)v.y, h2 = (f16)v.z, h3 = (f16)v.w;
    lh[q * 4 + 0][dl] = h0; ll[q * 4 + 0][dl] = (f16)(v.x - (float)h0);
    lh[q * 4 + 1][dl] = h1; ll[q * 4 + 1][dl] = (f16)(v.y - (float)h1);
    lh[q * 4 + 2][dl] = h2; ll[q * 4 + 2][dl] = (f16)(v.z - (float)h2);
    lh[q * 4 + 3][dl] = h3; ll[q * 4 + 3][dl] = (f16)(v.w - (float)h3);
    a0 = fmaf(v.x, v.x, a0); a1 = fmaf(v.y, v.y, a1);
    a2 = fmaf(v.z, v.z, a2); a3 = fmaf(v.w, v.w, a3);
  }
  __syncthreads();
  const int rl = threadIdx.x >> 2, seg = threadIdx.x & 3;
  f16* rowo = out + (size_t)(c0 + rl) * KP2 + d0;
#pragma unroll
  for (int j = 0; j < 4; ++j) {
    const int dd = seg * 16 + j * 4;
    f16x4 vh = *(const f16x4*)&lh[rl][dd];
    f16x4 vl = *(const f16x4*)&ll[rl][dd];
    *(f16x4*)&rowo[dd] = vh;
    *(f16x4*)&rowo[768 + dd] = vl;
  }
  if (!isX) {
    __syncthreads();
    float* sq = (float*)lh;   // 16 x 64 f32 = 4 KB
    sq[p * 64 + q * 4 + 0] = a0;
    sq[p * 64 + q * 4 + 1] = a1;
    sq[p * 64 + q * 4 + 2] = a2;
    sq[p * 64 + q * 4 + 3] = a3;
    __syncthreads();
    if (threadIdx.x < 64) {
      float s = 0.f;
#pragma unroll
      for (int pp = 0; pp < 16; ++pp) s += sq[pp * 64 + threadIdx.x];
      r2p[(size_t)blockIdx.y * N_REF + c0 + threadIdx.x] = s;
    }
  }
}

// ---------- sum 12 partials -> r2 (deterministic fixed order, ~2 us) ----------
__global__ __launch_bounds__(256)
void r2sum_kernel(const float* __restrict__ r2p, float* __restrict__ r2) {
  const int t = blockIdx.x * 256 + threadIdx.x;
  float s = 0.f;
#pragma unroll
  for (int k = 0; k < NDB; ++k) s += r2p[(size_t)k * N_REF + t];
  r2[t] = s;
}

// ---------- m97-geometry 128x128 f16-hi MFMA GEMM + fused approx top-4 ----------
// K-loop r11-verbatim. Epilogue reads SUMMED r2 (one load per ni — the r15
// inline 12-partial sum cost +18 us of epilogue latency, reverted).
__global__ __launch_bounds__(256, 2)
void mfma128_topk_kernel(const f16* __restrict__ A2, const f16* __restrict__ B2,
                         const float* __restrict__ r2g, u64* __restrict__ plist) {
  __shared__ __align__(16) char smem[33792];
  const int tid  = threadIdx.x;
  const int lane = tid & 63, wid = tid >> 6;
  const int wm = wid >> 1, wn = wid & 1;
  const int ln15 = lane & 15, g4 = lane >> 4;

  const int flat = (int)blockIdx.x;
  const int jj = flat >> 3;
  const int bx = (flat & 7) * 16 + (jj & 15);  // 0..127
  const int by = jj >> 4;                      // 0..15
  const int m0 = by * 128, n0 = bx * 128;

  const int s0 = tid, s1 = tid + 256;
  const int r0 = s0 >> 2, r1 = s1 >> 2;
  const int c0b = (((s0 & 3) ^ ((s0 >> 3) & 3)) << 4);
  const int c1b = (((s1 & 3) ^ ((s1 >> 3) & 3)) << 4);
  const char* gA0 = (const char*)(A2 + (size_t)(m0 + r0) * KP2) + c0b;
  const char* gA1 = (const char*)(A2 + (size_t)(m0 + r1) * KP2) + c1b;
  const char* gB0 = (const char*)(B2 + (size_t)(n0 + r0) * KP2) + c0b;
  const char* gB1 = (const char*)(B2 + (size_t)(n0 + r1) * KP2) + c1b;
  const int l0 = s0 * 16, l1 = s1 * 16;

#define STAGE_A(bufo, kbyte)                                     \
  { gl_lds16(gA0 + (kbyte), smem + (bufo) + l0);                 \
    gl_lds16(gA1 + (kbyte), smem + (bufo) + l1); }
#define STAGE_B(bufo, kbyte)                                     \
  { gl_lds16(gB0 + (kbyte), smem + (bufo) + 8192 + l0);          \
    gl_lds16(gB1 + (kbyte), smem + (bufo) + 8192 + l1); }

  const int cswz = ((g4 ^ ((ln15 >> 1) & 3)) << 4);
  int offA[4], offB[4];
#pragma unroll
  for (int mi = 0; mi < 4; ++mi) offA[mi] = (wm * 64 + mi * 16 + ln15) * 64 + cswz;
#pragma unroll
  for (int ni = 0; ni < 4; ++ni) offB[ni] = 8192 + (wn * 64 + ni * 16 + ln15) * 64 + cswz;

  f32x4 acc[4][4] = {};

  STAGE_A(0, 0);
  STAGE_B(0, 0);

  for (int kt = 0; kt < NT; ++kt) {
    const int dbuf = (kt & 1) << 14;
    const int sdb  = ((kt + 1) & 1) << 14;
    const int ktn = (kt + 1 < NT) ? kt + 1 : NT - 1;

    STAGE_A(sdb, ktn * 64);
    STAGE_B(sdb, ktn * 64);
    asm volatile("s_waitcnt vmcnt(4)" ::: "memory");
    asm volatile("s_barrier" ::: "memory");

    f16x8 a[4], b[4];
    a[0] = *(const f16x8*)(smem + dbuf + offA[0]);
    b[0] = *(const f16x8*)(smem + dbuf + offB[0]);
    a[1] = *(const f16x8*)(smem + dbuf + offA[1]);
    b[1] = *(const f16x8*)(smem + dbuf + offB[1]);
    a[2] = *(const f16x8*)(smem + dbuf + offA[2]);
    b[2] = *(const f16x8*)(smem + dbuf + offB[2]);
    a[3] = *(const f16x8*)(smem + dbuf + offA[3]);
    b[3] = *(const f16x8*)(smem + dbuf + offB[3]);

    __builtin_amdgcn_s_setprio(1);
#pragma unroll
    for (int mi = 0; mi < 4; ++mi)
#pragma unroll
      for (int ni = 0; ni < 4; ++ni)
        acc[mi][ni] = __builtin_amdgcn_mfma_f32_16x16x32_f16(a[mi], b[ni], acc[mi][ni], 0, 0, 0);
    __builtin_amdgcn_s_setprio(0);
    asm volatile("s_barrier" ::: "memory");
  }

  asm volatile("s_waitcnt vmcnt(0)" ::: "memory");
  __syncthreads();

  // ---- epilogue: scatter sortable-u32, per-row u64 top-4 per 64-col stripe ----
  float rv[4];
#pragma unroll
  for (int ni = 0; ni < 4; ++ni) rv[ni] = r2g[n0 + wn * 64 + ni * 16 + ln15];
  uint32_t* swu = (uint32_t*)smem + wid * 2112;   // [32][66] u32, wave-private
  const int rr = lane >> 1, hh = lane & 1;
  u64 keep[2][4];
#pragma unroll
  for (int P = 0; P < 2; ++P) {
#pragma unroll
    for (int mh = 0; mh < 2; ++mh)
#pragma unroll
      for (int ni = 0; ni < 4; ++ni)
#pragma unroll
        for (int r = 0; r < 4; ++r) {
          const int row_l = mh * 16 + g4 * 4 + r;   // C/D: col=lane&15, row=(lane>>4)*4+reg
          swu[row_l * 66 + ni * 16 + ln15] = fsort32(rv[ni] - 2.0f * acc[2 * P + mh][ni][r]);
        }
    asm volatile("s_waitcnt lgkmcnt(0)" ::: "memory");
    __builtin_amdgcn_sched_barrier(0);
    u64 s[4] = {~0ull, ~0ull, ~0ull, ~0ull};
    const uint32_t* rowp = swu + rr * 66 + hh * 32;
    const uint32_t cb = (uint32_t)(n0 + wn * 64 + hh * 32);
#pragma unroll
    for (int j = 0; j < 16; ++j) {
      const uint2 v = *(const uint2*)(rowp + j * 2);
      ins4u(s, ((u64)v.x << 32) | (cb + j * 2));
      ins4u(s, ((u64)v.y << 32) | (cb + j * 2 + 1));
    }
    u64 os[4];
#pragma unroll
    for (int j = 0; j < 4; ++j) os[j] = __shfl_xor((u64)s[j], 1);
    merge4u(s, os);
#pragma unroll
    for (int j = 0; j < 4; ++j) keep[P][j] = s[j];
    asm volatile("s_waitcnt lgkmcnt(0)" ::: "memory");
  }

  // ---- cross-wn merge: one 4-list per query row per block (NL = 128) ----
  __syncthreads();
  u64* lbuf = (u64*)smem;               // [128 rows][4] u64 = 4 KB
  if (wn == 1 && hh == 0) {
#pragma unroll
    for (int P = 0; P < 2; ++P) {
      const int lrow = wm * 64 + P * 32 + rr;
#pragma unroll
      for (int j = 0; j < 4; ++j) lbuf[lrow * 4 + j] = keep[P][j];
    }
  }
  __syncthreads();
  if (wn == 0 && hh == 0) {
#pragma unroll
    for (int P = 0; P < 2; ++P) {
      const int lrow = wm * 64 + P * 32 + rr;
      u64 o[4];
#pragma unroll
      for (int j = 0; j < 4; ++j) o[j] = lbuf[lrow * 4 + j];
      merge4u(keep[P], o);
      u64* dst = plist + ((size_t)(m0 + lrow) * NL + bx) * 4;
#pragma unroll
      for (int j = 0; j < 4; ++j) dst[j] = keep[P][j];
    }
  }
#undef STAGE_A
#undef STAGE_B
}

// ---------- fused select+rescore: 8 waves, wave w rescores candidate w ----------
__global__ __launch_bounds__(512)
void selres_kernel(const u64* __restrict__ plist,
                   const f16* __restrict__ A2, const f16* __restrict__ B2,
                   const float* __restrict__ r2, int* __restrict__ final4) {
  const int t = blockIdx.x;
  const int lane = threadIdx.x & 63, wid = threadIdx.x >> 6;
  __shared__ int cids[8];
  __shared__ float scs[8];

  if (wid == 0) {
    u64 s[8];
#pragma unroll
    for (int j = 0; j < 8; ++j) s[j] = ~0ull;
#pragma unroll
    for (int li = 0; li < 2; ++li) {
      const u64* src = plist + ((size_t)t * NL + lane * 2 + li) * 4;
      u64 o[8] = {src[0], src[1], src[2], src[3], ~0ull, ~0ull, ~0ull, ~0ull};
      merge8u(s, o);
    }
#pragma unroll
    for (int mask = 1; mask < 64; mask <<= 1) {
      u64 o[8];
#pragma unroll
      for (int j = 0; j < 8; ++j) o[j] = __shfl_xor((u64)s[j], mask);
      merge8u(s, o);
    }
    if (lane == 0) {
#pragma unroll
      for (int j = 0; j < 8; ++j) cids[j] = (int)(uint32_t)s[j];
    }
  }
  __syncthreads();

  const int cid = cids[wid];
  const f16* xrow = A2 + (size_t)t * KP2;
  const f16* rrow = B2 + (size_t)cid * KP2;
  float acc = 0.f;
#pragma unroll
  for (int k = 0; k < 12; ++k) {
    const float xhv = (float)xrow[lane + 64 * k];
    const float xlv = (float)xrow[768 + lane + 64 * k];
    const float rh = (float)rrow[lane + 64 * k];
    const float rl = (float)rrow[768 + lane + 64 * k];
    acc = fmaf(xhv, rh, acc);
    acc = fmaf(xhv, rl, acc);
    acc = fmaf(xlv, rh, acc);
  }
#pragma unroll
  for (int m = 1; m < 64; m <<= 1) acc += __shfl_xor(acc, m);
  if (lane == 0) scs[wid] = r2[cid] - 2.0f * acc;
  __syncthreads();

  if (threadIdx.x == 0) {
    float s4[4] = {1e30f, 1e30f, 1e30f, 1e30f};
    int   i4[4] = {0x7fffffff, 0x7fffffff, 0x7fffffff, 0x7fffffff};
#pragma unroll
    for (int j = 0; j < 8; ++j) insert4(s4, i4, scs[j], cids[j]);
    int4 o; o.x = i4[0]; o.y = i4[1]; o.z = i4[2]; o.w = i4[3];
    *(int4*)&final4[t * 4] = o;
  }
}

// ---------- gather from B2 rows (coalesced) + LDS transpose -> out [d][T] ----------
__global__ __launch_bounds__(256)
void gatherB2_kernel(const f16* __restrict__ B2, const int* __restrict__ final4,
                     float* __restrict__ out) {
  __shared__ int ids[64][4];
  __shared__ float tr[64][129];
  const int tid = threadIdx.x;
  const int t0 = blockIdx.x * 64;
  const int d0 = blockIdx.y * 128;
  ((int*)ids)[tid] = final4[t0 * 4 + tid];
  __syncthreads();

  const int q = tid >> 2, dp = tid & 3;
  float a[32];
#pragma unroll
  for (int k = 0; k < 32; ++k) a[k] = 0.f;
#pragma unroll
  for (int j = 0; j < 4; ++j) {
    const f16* row = B2 + (size_t)ids[q][j] * KP2 + d0 + dp * 32;
#pragma unroll
    for (int v = 0; v < 4; ++v) {
      const f16x8 h = *(const f16x8*)(row + v * 8);
      const f16x8 l = *(const f16x8*)(row + 768 + v * 8);
#pragma unroll
      for (int e = 0; e < 8; ++e) a[v * 8 + e] += (float)h[e] + (float)l[e];
    }
  }
#pragma unroll
  for (int k = 0; k < 32; ++k) tr[q][dp * 32 + k] = 0.25f * a[k];
  __syncthreads();

  const int dd = tid >> 1, hf = tid & 1;
  float* orow = out + (size_t)(d0 + dd) * T_Q + t0 + hf * 32;
#pragma unroll
  for (int k = 0; k < 8; ++k) {
    float4 v4;
    v4.x = tr[hf * 32 + k * 4 + 0][dd];
    v4.y = tr[hf * 32 + k * 4 + 1][dd];
    v4.z = tr[hf * 32 + k * 4 + 2][dd];
    v4.w = tr[hf * 32 + k * 4 + 3][dd];
    *(float4*)(orow + k * 4) = v4;
  }
}

// ---------- fallback fp32 pipeline (round-1, known correct) ----------
__global__ __launch_bounds__(256)
void r2_kernel(const float* __restrict__ R, float* __restrict__ r2) {
  __shared__ float red[256];
  const int lane = threadIdx.x & 63;
  const int dg   = threadIdx.x >> 6;
  const int n    = blockIdx.x * 64 + lane;
  float acc = 0.f;
  const int d0 = dg * (DIM / 4), d1 = d0 + (DIM / 4);
  for (int d = d0; d < d1; ++d) {
    float v = R[(size_t)d * N_REF + n];
    acc += v * v;
  }
  red[threadIdx.x] = acc;
  __syncthreads();
  if (threadIdx.x < 64)
    r2[n] = red[lane] + red[lane + 64] + red[lane + 128] + red[lane + 192];
}

__global__ __launch_bounds__(256)
void gather_kernel(const float* __restrict__ R, const int* __restrict__ final4,
                   float* __restrict__ out) {
  __shared__ int ids[64][4];
  const int tx = threadIdx.x & 63, ty = threadIdx.x >> 6;
  const int t0 = blockIdx.x * 64;
  ((int*)ids)[threadIdx.x] = final4[t0 * 4 + threadIdx.x];
  __syncthreads();
  const int d = blockIdx.y * 4 + ty;
  const float* row = R + (size_t)d * N_REF;
  const float sum = row[ids[tx][0]] + row[ids[tx][1]] + row[ids[tx][2]] + row[ids[tx][3]];
  out[(size_t)d * T_Q + t0 + tx] = 0.25f * sum;
}

#define FBM 64
#define FBN 256
#define FBK 16
#define FNL (N_REF / FBN)
__global__ __launch_bounds__(256)
void score_topk_kernel(const float* __restrict__ X, const float* __restrict__ R,
                       const float* __restrict__ r2,
                       float* __restrict__ pscore, int* __restrict__ pidx) {
  __shared__ float As[FBK][FBM];
  __shared__ float Bs[FBK][FBN];
  __shared__ float r2s[FBN];
  const int tid = threadIdx.x;
  const int tx = tid & 15, ty = tid >> 4;
  const int m0 = blockIdx.y * FBM;
  const int n0 = blockIdx.x * FBN;
  r2s[tid] = r2[n0 + tid];
  float acc[4][16];
#pragma unroll
  for (int i = 0; i < 4; ++i)
#pragma unroll
    for (int j = 0; j < 16; ++j) acc[i][j] = 0.f;
  for (int k0 = 0; k0 < DIM; k0 += FBK) {
    {
      const int k = tid >> 4, m4 = tid & 15;
      const float4 av = *(const float4*)&X[(size_t)(k0 + k) * T_Q + m0 + m4 * 4];
      *(float4*)&As[k][m4 * 4] = av;
    }
#pragma unroll
    for (int i = 0; i < 4; ++i) {
      const int idx4 = tid + i * 256;
      const int k = idx4 >> 6, n4 = idx4 & 63;
      const float4 bv = *(const float4*)&R[(size_t)(k0 + k) * N_REF + n0 + n4 * 4];
      *(float4*)&Bs[k][n4 * 4] = bv;
    }
    __syncthreads();
#pragma unroll
    for (int k = 0; k < FBK; ++k) {
      float av[4], bv[16];
      *(float4*)av = *(const float4*)&As[k][ty * 4];
#pragma unroll
      for (int c = 0; c < 4; ++c)
        *(float4*)&bv[c * 4] = *(const float4*)&Bs[k][tx * 4 + c * 64];
#pragma unroll
      for (int mi = 0; mi < 4; ++mi)
#pragma unroll
        for (int ni = 0; ni < 16; ++ni) acc[mi][ni] += av[mi] * bv[ni];
    }
    __syncthreads();
  }
#pragma unroll
  for (int mi = 0; mi < 4; ++mi) {
    float s[4]  = {1e30f, 1e30f, 1e30f, 1e30f};
    int   id[4] = {0x7fffffff, 0x7fffffff, 0x7fffffff, 0x7fffffff};
#pragma unroll
    for (int c = 0; c < 4; ++c)
#pragma unroll
      for (int j = 0; j < 4; ++j) {
        const int nl = tx * 4 + c * 64 + j;
        const float sc = r2s[nl] - 2.0f * acc[mi][c * 4 + j];
        insert4(s, id, sc, n0 + nl);
      }
#pragma unroll
    for (int mask = 1; mask < 16; mask <<= 1) {
      float os[4]; int oid[4];
#pragma unroll
      for (int j = 0; j < 4; ++j) {
        os[j]  = __shfl_xor(s[j], mask);
        oid[j] = __shfl_xor(id[j], mask);
      }
      merge_top4(s, id, os, oid);
    }
    if (tx == 0) {
      const int t = m0 + ty * 4 + mi;
      const int base = (t * FNL + (int)blockIdx.x) * 4;
#pragma unroll
      for (int j = 0; j < 4; ++j) { pscore[base + j] = s[j]; pidx[base + j] = id[j]; }
    }
  }
}

template <int NLISTS>
__global__ __launch_bounds__(64)
void select_kernel(const float* __restrict__ pscore, const int* __restrict__ pidx,
                   int* __restrict__ final4) {
  const int t = blockIdx.x, lane = threadIdx.x;
  constexpr int LPL = NLISTS / 64;
  float s[4]  = {1e30f, 1e30f, 1e30f, 1e30f};
  int   id[4] = {0x7fffffff, 0x7fffffff, 0x7fffffff, 0x7fffffff};
#pragma unroll
  for (int li = 0; li < LPL; ++li) {
    const int base = (t * NLISTS + lane * LPL + li) * 4;
    const float4 sv = *(const float4*)&pscore[base];
    const int4   iv = *(const int4*)&pidx[base];
    float os[4] = {sv.x, sv.y, sv.z, sv.w};
    int  oid[4] = {iv.x, iv.y, iv.z, iv.w};
    merge_top4(s, id, os, oid);
  }
#pragma unroll
  for (int mask = 1; mask < 64; mask <<= 1) {
    float os[4]; int oid[4];
#pragma unroll
    for (int j = 0; j < 4; ++j) {
      os[j]  = __shfl_xor(s[j], mask);
      oid[j] = __shfl_xor(id[j], mask);
    }
    merge_top4(s, id, os, oid);
  }
  if (lane == 0) {
    int4 o; o.x = id[0]; o.y = id[1]; o.z = id[2]; o.w = id[3];
    *(int4*)&final4[t * 4] = o;
  }
}

extern "C" void kernel_launch(void* const* d_in, const int* in_sizes, int n_in,
                              void* d_out, int out_size, void* d_ws, size_t ws_size,
                              hipStream_t stream) {
  const float* X = (const float*)d_in[0];   // [768][2048]
  const float* R = (const float*)d_in[1];   // [768][16384]
  float* out = (float*)d_out;               // [768][2048]

  const size_t szA2 = (size_t)T_Q * KP2 * sizeof(f16);        // 6,291,456
  const size_t szB2 = (size_t)N_REF * KP2 * sizeof(f16);      // 50,331,648
  const size_t szRP = (size_t)NDB * N_REF * sizeof(float);    // 786,432
  const size_t szr2 = (size_t)N_REF * sizeof(float);          // 65,536
  const size_t szPL = (size_t)T_Q * NL * 4 * sizeof(u64);     // 8,388,608
  const size_t need = szA2 + szB2 + szRP + szr2 + szPL +
                      (size_t)T_Q * 4 * sizeof(int);

  if (ws_size >= need) {
    char* w = (char*)d_ws;
    f16* A2 = (f16*)w;            w += szA2;
    f16* B2 = (f16*)w;            w += szB2;
    float* r2p    = (float*)w;    w += szRP;
    float* r2     = (float*)w;    w += szr2;
    u64*   plist  = (u64*)w;      w += szPL;
    int*   final4 = (int*)w;

    hipLaunchKernelGGL(tsplit2_kernel, dim3(T_Q / 64 + N_REF / 64, NDB), dim3(256), 0,
                       stream, X, R, A2, B2, r2p);
    hipLaunchKernelGGL(r2sum_kernel, dim3(N_REF / 256), dim3(256), 0, stream, r2p, r2);
    hipLaunchKernelGGL(mfma128_topk_kernel, dim3((N_REF / 128) * (T_Q / 128)), dim3(256), 0,
                       stream, A2, B2, r2, plist);
    hipLaunchKernelGGL(selres_kernel, dim3(T_Q), dim3(512), 0, stream,
                       plist, A2, B2, r2, final4);
    hipLaunchKernelGGL(gatherB2_kernel, dim3(T_Q / 64, DIM / 128), dim3(256), 0, stream,
                       B2, final4, out);
  } else {
    // fallback: fp32 pipeline (~4.2 MB ws)
    char* w = (char*)d_ws;
    float* r2     = (float*)w;  w += szr2;
    float* pscore = (float*)w;  w += (size_t)T_Q * FNL * 4 * sizeof(float);
    int*   pidx   = (int*)w;    w += (size_t)T_Q * FNL * 4 * sizeof(int);
    int*   final4 = (int*)w;

    hipLaunchKernelGGL(r2_kernel, dim3(N_REF / 64), dim3(256), 0, stream, R, r2);
    hipLaunchKernelGGL(score_topk_kernel, dim3(N_REF / FBN, T_Q / FBM), dim3(256), 0, stream,
                       X, R, r2, pscore, pidx);
    hipLaunchKernelGGL((select_kernel<FNL>), dim3(T_Q), dim3(64), 0, stream,
                       pscore, pidx, final4);
    hipLaunchKernelGGL(gather_kernel, dim3(T_Q / 64, DIM / 4), dim3(256), 0, stream,
                       R, final4, out);
  }
}

// Round 17
// 135.099 us; speedup vs baseline: 1.1955x; 1.0085x over previous
//
#include <hip/hip_runtime.h>
#include <stdint.h>

#define T_Q   2048
#define N_REF 16384
#define DIM   768
#define KP2   1536        // packed K cols: [hi | lo]
#define NT    24          // K = 768 = 24 tiles of 32 (hi limb only)
#define NL    128         // partial top-4 lists per query (128-col block stripes)
#define NDB   (DIM / 64)  // 12 d-blocks for partial r2

using f16   = _Float16;
using f16x4 = __attribute__((ext_vector_type(4))) _Float16;
using f16x8 = __attribute__((ext_vector_type(8))) _Float16;
using f32x4 = __attribute__((ext_vector_type(4))) float;
typedef unsigned long long u64;

// ---------- exact-path lexicographic top-4 (float score, int idx) ----------
__device__ __forceinline__ bool lex_less(float sa, int ia, float sb, int ib) {
  return (sa < sb) || (sa == sb && ia < ib);
}
#define CE_PAIR(s0, i0, s1, i1)                                        \
  { if (lex_less(s1, i1, s0, i0)) { float _ts = s0; s0 = s1; s1 = _ts; \
                                    int _ti = i0; i0 = i1; i1 = _ti; } }
#define PICKMIN(as, ai, bs, bi, rs, ri)                   \
  { if (lex_less(bs, bi, as, ai)) { rs = bs; ri = bi; }   \
    else                          { rs = as; ri = ai; } }

__device__ __forceinline__ void insert4(float s[4], int id[4], float sc, int n) {
  if (lex_less(sc, n, s[3], id[3])) {
    s[3] = sc; id[3] = n;
    CE_PAIR(s[2], id[2], s[3], id[3]);
    CE_PAIR(s[1], id[1], s[2], id[2]);
    CE_PAIR(s[0], id[0], s[1], id[1]);
  }
}
__device__ __forceinline__ void merge_top4(float s[4], int id[4],
                                           const float os[4], const int oid[4]) {
  float l0, l1, l2, l3; int j0, j1, j2, j3;
  PICKMIN(s[0], id[0], os[3], oid[3], l0, j0);
  PICKMIN(s[1], id[1], os[2], oid[2], l1, j1);
  PICKMIN(s[2], id[2], os[1], oid[1], l2, j2);
  PICKMIN(s[3], id[3], os[0], oid[0], l3, j3);
  CE_PAIR(l0, j0, l2, j2);
  CE_PAIR(l1, j1, l3, j3);
  CE_PAIR(l0, j0, l1, j1);
  CE_PAIR(l2, j2, l3, j3);
  s[0] = l0; s[1] = l1; s[2] = l2; s[3] = l3;
  id[0] = j0; id[1] = j1; id[2] = j2; id[3] = j3;
}

// ---------- packed-u64 ranking: (sortable_score32 << 32) | col ----------
__device__ __forceinline__ uint32_t fsort32(float f) {
  uint32_t u = __float_as_uint(f);
  return ((int)u < 0) ? ~u : (u | 0x80000000u);
}
__device__ __forceinline__ void ins4u(u64 s[4], u64 c) {
  if (c < s[3]) {
    s[3] = c;
    if (s[3] < s[2]) { u64 t = s[2]; s[2] = s[3]; s[3] = t; }
    if (s[2] < s[1]) { u64 t = s[1]; s[1] = s[2]; s[2] = t; }
    if (s[1] < s[0]) { u64 t = s[0]; s[0] = s[1]; s[1] = t; }
  }
}
#define CEU(a, b) { u64 _mn = (a) < (b) ? (a) : (b); \
                    u64 _mx = (a) < (b) ? (b) : (a); (a) = _mn; (b) = _mx; }
__device__ __forceinline__ void merge4u(u64 s[4], const u64 o[4]) {
  u64 l0 = s[0] < o[3] ? s[0] : o[3];
  u64 l1 = s[1] < o[2] ? s[1] : o[2];
  u64 l2 = s[2] < o[1] ? s[2] : o[1];
  u64 l3 = s[3] < o[0] ? s[3] : o[0];
  CEU(l0, l2); CEU(l1, l3); CEU(l0, l1); CEU(l2, l3);
  s[0] = l0; s[1] = l1; s[2] = l2; s[3] = l3;
}
__device__ __forceinline__ void merge8u(u64 s[8], const u64 o[8]) {
  u64 l0 = s[0] < o[7] ? s[0] : o[7];
  u64 l1 = s[1] < o[6] ? s[1] : o[6];
  u64 l2 = s[2] < o[5] ? s[2] : o[5];
  u64 l3 = s[3] < o[4] ? s[3] : o[4];
  u64 l4 = s[4] < o[3] ? s[4] : o[3];
  u64 l5 = s[5] < o[2] ? s[5] : o[2];
  u64 l6 = s[6] < o[1] ? s[6] : o[1];
  u64 l7 = s[7] < o[0] ? s[7] : o[0];
  CEU(l0, l4); CEU(l1, l5); CEU(l2, l6); CEU(l3, l7);
  CEU(l0, l2); CEU(l1, l3); CEU(l4, l6); CEU(l5, l7);
  CEU(l0, l1); CEU(l2, l3); CEU(l4, l5); CEU(l6, l7);
  s[0]=l0; s[1]=l1; s[2]=l2; s[3]=l3; s[4]=l4; s[5]=l5; s[6]=l6; s[7]=l7;
}

__device__ __forceinline__ void gl_lds16(const void* g, void* l) {
  __builtin_amdgcn_global_load_lds((const __attribute__((address_space(1))) uint32_t*)g,
                                   (__attribute__((address_space(3))) uint32_t*)l, 16, 0, 0);
}

// ---------- fused transpose + f16 hi/lo split for X AND R (+ partial r2) ----------
__global__ __launch_bounds__(256)
void tsplit2_kernel(const float* __restrict__ X, const float* __restrict__ R,
                    f16* __restrict__ A2, f16* __restrict__ B2,
                    float* __restrict__ r2p) {
  __shared__ f16 lh[64][66], ll[64][66];
  const int bxg = (int)blockIdx.x;
  const bool isX = bxg < (T_Q / 64);
  const float* in = isX ? X : R;
  const int W = isX ? T_Q : N_REF;
  f16* out = isX ? A2 : B2;
  const int c0 = (isX ? bxg : bxg - T_Q / 64) * 64;
  const int d0 = blockIdx.y * 64;
  const int q = threadIdx.x & 15, p = threadIdx.x >> 4;
  float a0 = 0.f, a1 = 0.f, a2 = 0.f, a3 = 0.f;
#pragma unroll
  for (int i = 0; i < 4; ++i) {
    const int dl = p + i * 16;
    const float4 v = *(const float4*)&in[(size_t)(d0 + dl) * W + c0 + q * 4];
    const f16 h0 = (f16)v.x, h1 = (f16)v.y, h2 = (f16)v.z, h3 = (f16)v.w;
    lh[q * 4 + 0][dl] = h0; ll[q * 4 + 0][dl] = (f16)(v.x - (float)h0);
    lh[q * 4 + 1][dl] = h1; ll[q * 4 + 1][dl] = (f16)(v.y - (float)h1);
    lh[q * 4 + 2][dl] = h2; ll[q * 4 + 2][dl] = (f16)(v.z - (float)h2);
    lh[q * 4 + 3][dl] = h3; ll[q * 4 + 3][dl] = (f16)(v.w - (float)h3);
    a0 = fmaf(v.x, v.x, a0); a1 = fmaf(v.y, v.y, a1);
    a2 = fmaf(v.z, v.z, a2); a3 = fmaf(v.w, v.w, a3);
  }
  __syncthreads();
  const int rl = threadIdx.x >> 2, seg = threadIdx.x & 3;
  f16* rowo = out + (size_t)(c0 + rl) * KP2 + d0;
#pragma unroll
  for (int j = 0; j < 4; ++j) {
    const int dd = seg * 16 + j * 4;
    f16x4 vh = *(const f16x4*)&lh[rl][dd];
    f16x4 vl = *(const f16x4*)&ll[rl][dd];
    *(f16x4*)&rowo[dd] = vh;
    *(f16x4*)&rowo[768 + dd] = vl;
  }
  if (!isX) {
    __syncthreads();
    float* sq = (float*)lh;   // 16 x 64 f32 = 4 KB
    sq[p * 64 + q * 4 + 0] = a0;
    sq[p * 64 + q * 4 + 1] = a1;
    sq[p * 64 + q * 4 + 2] = a2;
    sq[p * 64 + q * 4 + 3] = a3;
    __syncthreads();
    if (threadIdx.x < 64) {
      float s = 0.f;
#pragma unroll
      for (int pp = 0; pp < 16; ++pp) s += sq[pp * 64 + threadIdx.x];
      r2p[(size_t)blockIdx.y * N_REF + c0 + threadIdx.x] = s;
    }
  }
}

// ---------- sum 12 partials -> r2 (deterministic fixed order, ~2 us) ----------
__global__ __launch_bounds__(256)
void r2sum_kernel(const float* __restrict__ r2p, float* __restrict__ r2) {
  const int t = blockIdx.x * 256 + threadIdx.x;
  float s = 0.f;
#pragma unroll
  for (int k = 0; k < NDB; ++k) s += r2p[(size_t)k * N_REF + t];
  r2[t] = s;
}

// ---------- m97-geometry 128x128 f16-hi MFMA GEMM + fused approx top-4 ----------
// launch_bounds(256,4): register footprint is exactly 128 unified (64 VGPR +
// 64 AGPR acc) -> cap 128 reproduces current codegen but guarantees 4 blocks/CU.
__global__ __launch_bounds__(256, 4)
void mfma128_topk_kernel(const f16* __restrict__ A2, const f16* __restrict__ B2,
                         const float* __restrict__ r2g, u64* __restrict__ plist) {
  __shared__ __align__(16) char smem[33792];
  const int tid  = threadIdx.x;
  const int lane = tid & 63, wid = tid >> 6;
  const int wm = wid >> 1, wn = wid & 1;
  const int ln15 = lane & 15, g4 = lane >> 4;

  const int flat = (int)blockIdx.x;
  const int jj = flat >> 3;
  const int bx = (flat & 7) * 16 + (jj & 15);  // 0..127
  const int by = jj >> 4;                      // 0..15
  const int m0 = by * 128, n0 = bx * 128;

  const int s0 = tid, s1 = tid + 256;
  const int r0 = s0 >> 2, r1 = s1 >> 2;
  const int c0b = (((s0 & 3) ^ ((s0 >> 3) & 3)) << 4);
  const int c1b = (((s1 & 3) ^ ((s1 >> 3) & 3)) << 4);
  const char* gA0 = (const char*)(A2 + (size_t)(m0 + r0) * KP2) + c0b;
  const char* gA1 = (const char*)(A2 + (size_t)(m0 + r1) * KP2) + c1b;
  const char* gB0 = (const char*)(B2 + (size_t)(n0 + r0) * KP2) + c0b;
  const char* gB1 = (const char*)(B2 + (size_t)(n0 + r1) * KP2) + c1b;
  const int l0 = s0 * 16, l1 = s1 * 16;

#define STAGE_A(bufo, kbyte)                                     \
  { gl_lds16(gA0 + (kbyte), smem + (bufo) + l0);                 \
    gl_lds16(gA1 + (kbyte), smem + (bufo) + l1); }
#define STAGE_B(bufo, kbyte)                                     \
  { gl_lds16(gB0 + (kbyte), smem + (bufo) + 8192 + l0);          \
    gl_lds16(gB1 + (kbyte), smem + (bufo) + 8192 + l1); }

  const int cswz = ((g4 ^ ((ln15 >> 1) & 3)) << 4);
  int offA[4], offB[4];
#pragma unroll
  for (int mi = 0; mi < 4; ++mi) offA[mi] = (wm * 64 + mi * 16 + ln15) * 64 + cswz;
#pragma unroll
  for (int ni = 0; ni < 4; ++ni) offB[ni] = 8192 + (wn * 64 + ni * 16 + ln15) * 64 + cswz;

  f32x4 acc[4][4] = {};

  STAGE_A(0, 0);
  STAGE_B(0, 0);

  for (int kt = 0; kt < NT; ++kt) {
    const int dbuf = (kt & 1) << 14;
    const int sdb  = ((kt + 1) & 1) << 14;
    const int ktn = (kt + 1 < NT) ? kt + 1 : NT - 1;

    STAGE_A(sdb, ktn * 64);
    STAGE_B(sdb, ktn * 64);
    asm volatile("s_waitcnt vmcnt(4)" ::: "memory");
    asm volatile("s_barrier" ::: "memory");

    f16x8 a[4], b[4];
    a[0] = *(const f16x8*)(smem + dbuf + offA[0]);
    b[0] = *(const f16x8*)(smem + dbuf + offB[0]);
    a[1] = *(const f16x8*)(smem + dbuf + offA[1]);
    b[1] = *(const f16x8*)(smem + dbuf + offB[1]);
    a[2] = *(const f16x8*)(smem + dbuf + offA[2]);
    b[2] = *(const f16x8*)(smem + dbuf + offB[2]);
    a[3] = *(const f16x8*)(smem + dbuf + offA[3]);
    b[3] = *(const f16x8*)(smem + dbuf + offB[3]);

    __builtin_amdgcn_s_setprio(1);
#pragma unroll
    for (int mi = 0; mi < 4; ++mi)
#pragma unroll
      for (int ni = 0; ni < 4; ++ni)
        acc[mi][ni] = __builtin_amdgcn_mfma_f32_16x16x32_f16(a[mi], b[ni], acc[mi][ni], 0, 0, 0);
    __builtin_amdgcn_s_setprio(0);
    asm volatile("s_barrier" ::: "memory");
  }

  asm volatile("s_waitcnt vmcnt(0)" ::: "memory");
  __syncthreads();

  // ---- epilogue: scatter sortable-u32, per-row u64 top-4 per 64-col stripe ----
  float rv[4];
#pragma unroll
  for (int ni = 0; ni < 4; ++ni) rv[ni] = r2g[n0 + wn * 64 + ni * 16 + ln15];
  uint32_t* swu = (uint32_t*)smem + wid * 2112;   // [32][66] u32, wave-private
  const int rr = lane >> 1, hh = lane & 1;
  u64 keep[2][4];
#pragma unroll
  for (int P = 0; P < 2; ++P) {
#pragma unroll
    for (int mh = 0; mh < 2; ++mh)
#pragma unroll
      for (int ni = 0; ni < 4; ++ni)
#pragma unroll
        for (int r = 0; r < 4; ++r) {
          const int row_l = mh * 16 + g4 * 4 + r;   // C/D: col=lane&15, row=(lane>>4)*4+reg
          swu[row_l * 66 + ni * 16 + ln15] = fsort32(rv[ni] - 2.0f * acc[2 * P + mh][ni][r]);
        }
    asm volatile("s_waitcnt lgkmcnt(0)" ::: "memory");
    __builtin_amdgcn_sched_barrier(0);
    u64 s[4] = {~0ull, ~0ull, ~0ull, ~0ull};
    const uint32_t* rowp = swu + rr * 66 + hh * 32;
    const uint32_t cb = (uint32_t)(n0 + wn * 64 + hh * 32);
#pragma unroll
    for (int j = 0; j < 16; ++j) {
      const uint2 v = *(const uint2*)(rowp + j * 2);
      ins4u(s, ((u64)v.x << 32) | (cb + j * 2));
      ins4u(s, ((u64)v.y << 32) | (cb + j * 2 + 1));
    }
    u64 os[4];
#pragma unroll
    for (int j = 0; j < 4; ++j) os[j] = __shfl_xor((u64)s[j], 1);
    merge4u(s, os);
#pragma unroll
    for (int j = 0; j < 4; ++j) keep[P][j] = s[j];
    asm volatile("s_waitcnt lgkmcnt(0)" ::: "memory");
  }

  // ---- cross-wn merge: one 4-list per query row per block (NL = 128) ----
  __syncthreads();
  u64* lbuf = (u64*)smem;               // [128 rows][4] u64 = 4 KB
  if (wn == 1 && hh == 0) {
#pragma unroll
    for (int P = 0; P < 2; ++P) {
      const int lrow = wm * 64 + P * 32 + rr;
#pragma unroll
      for (int j = 0; j < 4; ++j) lbuf[lrow * 4 + j] = keep[P][j];
    }
  }
  __syncthreads();
  if (wn == 0 && hh == 0) {
#pragma unroll
    for (int P = 0; P < 2; ++P) {
      const int lrow = wm * 64 + P * 32 + rr;
      u64 o[4];
#pragma unroll
      for (int j = 0; j < 4; ++j) o[j] = lbuf[lrow * 4 + j];
      merge4u(keep[P], o);
      u64* dst = plist + ((size_t)(m0 + lrow) * NL + bx) * 4;
#pragma unroll
      for (int j = 0; j < 4; ++j) dst[j] = keep[P][j];
    }
  }
#undef STAGE_A
#undef STAGE_B
}

// ---------- fused select+rescore: 8 waves, wave w rescores candidate w ----------
__global__ __launch_bounds__(512)
void selres_kernel(const u64* __restrict__ plist,
                   const f16* __restrict__ A2, const f16* __restrict__ B2,
                   const float* __restrict__ r2, int* __restrict__ final4) {
  const int t = blockIdx.x;
  const int lane = threadIdx.x & 63, wid = threadIdx.x >> 6;
  __shared__ int cids[8];
  __shared__ float scs[8];

  if (wid == 0) {
    u64 s[8];
#pragma unroll
    for (int j = 0; j < 8; ++j) s[j] = ~0ull;
#pragma unroll
    for (int li = 0; li < 2; ++li) {
      const u64* src = plist + ((size_t)t * NL + lane * 2 + li) * 4;
      u64 o[8] = {src[0], src[1], src[2], src[3], ~0ull, ~0ull, ~0ull, ~0ull};
      merge8u(s, o);
    }
#pragma unroll
    for (int mask = 1; mask < 64; mask <<= 1) {
      u64 o[8];
#pragma unroll
      for (int j = 0; j < 8; ++j) o[j] = __shfl_xor((u64)s[j], mask);
      merge8u(s, o);
    }
    if (lane == 0) {
#pragma unroll
      for (int j = 0; j < 8; ++j) cids[j] = (int)(uint32_t)s[j];
    }
  }
  __syncthreads();

  const int cid = cids[wid];
  const f16* xrow = A2 + (size_t)t * KP2;
  const f16* rrow = B2 + (size_t)cid * KP2;
  float acc = 0.f;
#pragma unroll
  for (int k = 0; k < 12; ++k) {
    const float xhv = (float)xrow[lane + 64 * k];
    const float xlv = (float)xrow[768 + lane + 64 * k];
    const float rh = (float)rrow[lane + 64 * k];
    const float rl = (float)rrow[768 + lane + 64 * k];
    acc = fmaf(xhv, rh, acc);
    acc = fmaf(xhv, rl, acc);
    acc = fmaf(xlv, rh, acc);
  }
#pragma unroll
  for (int m = 1; m < 64; m <<= 1) acc += __shfl_xor(acc, m);
  if (lane == 0) scs[wid] = r2[cid] - 2.0f * acc;
  __syncthreads();

  if (threadIdx.x == 0) {
    float s4[4] = {1e30f, 1e30f, 1e30f, 1e30f};
    int   i4[4] = {0x7fffffff, 0x7fffffff, 0x7fffffff, 0x7fffffff};
#pragma unroll
    for (int j = 0; j < 8; ++j) insert4(s4, i4, scs[j], cids[j]);
    int4 o; o.x = i4[0]; o.y = i4[1]; o.z = i4[2]; o.w = i4[3];
    *(int4*)&final4[t * 4] = o;
  }
}

// ---------- gather from B2 rows (coalesced) + LDS transpose -> out [d][T] ----------
// grid (32, 12): 64-d chunks for 2x the parallelism of the 128-d version.
__global__ __launch_bounds__(256)
void gatherB2_kernel(const f16* __restrict__ B2, const int* __restrict__ final4,
                     float* __restrict__ out) {
  __shared__ int ids[64][4];
  __shared__ float tr[64][65];
  const int tid = threadIdx.x;
  const int t0 = blockIdx.x * 64;
  const int d0 = blockIdx.y * 64;
  ((int*)ids)[tid] = final4[t0 * 4 + tid];
  __syncthreads();

  const int q = tid >> 2, dp = tid & 3;   // query q, d-span dp*16..+16
  float a[16];
#pragma unroll
  for (int k = 0; k < 16; ++k) a[k] = 0.f;
#pragma unroll
  for (int j = 0; j < 4; ++j) {
    const f16* row = B2 + (size_t)ids[q][j] * KP2 + d0 + dp * 16;
#pragma unroll
    for (int v = 0; v < 2; ++v) {
      const f16x8 h = *(const f16x8*)(row + v * 8);
      const f16x8 l = *(const f16x8*)(row + 768 + v * 8);
#pragma unroll
      for (int e = 0; e < 8; ++e) a[v * 8 + e] += (float)h[e] + (float)l[e];
    }
  }
#pragma unroll
  for (int k = 0; k < 16; ++k) tr[q][dp * 16 + k] = 0.25f * a[k];
  __syncthreads();

  // write: thread (dd = tid>>2, seg = tid&3) emits 16 consecutive t's of row d0+dd
  const int dd = tid >> 2, seg = tid & 3;
  float* orow = out + (size_t)(d0 + dd) * T_Q + t0 + seg * 16;
#pragma unroll
  for (int k = 0; k < 4; ++k) {
    float4 v4;
    v4.x = tr[seg * 16 + k * 4 + 0][dd];
    v4.y = tr[seg * 16 + k * 4 + 1][dd];
    v4.z = tr[seg * 16 + k * 4 + 2][dd];
    v4.w = tr[seg * 16 + k * 4 + 3][dd];
    *(float4*)(orow + k * 4) = v4;
  }
}

// ---------- fallback fp32 pipeline (round-1, known correct) ----------
__global__ __launch_bounds__(256)
void r2_kernel(const float* __restrict__ R, float* __restrict__ r2) {
  __shared__ float red[256];
  const int lane = threadIdx.x & 63;
  const int dg   = threadIdx.x >> 6;
  const int n    = blockIdx.x * 64 + lane;
  float acc = 0.f;
  const int d0 = dg * (DIM / 4), d1 = d0 + (DIM / 4);
  for (int d = d0; d < d1; ++d) {
    float v = R[(size_t)d * N_REF + n];
    acc += v * v;
  }
  red[threadIdx.x] = acc;
  __syncthreads();
  if (threadIdx.x < 64)
    r2[n] = red[lane] + red[lane + 64] + red[lane + 128] + red[lane + 192];
}

__global__ __launch_bounds__(256)
void gather_kernel(const float* __restrict__ R, const int* __restrict__ final4,
                   float* __restrict__ out) {
  __shared__ int ids[64][4];
  const int tx = threadIdx.x & 63, ty = threadIdx.x >> 6;
  const int t0 = blockIdx.x * 64;
  ((int*)ids)[threadIdx.x] = final4[t0 * 4 + threadIdx.x];
  __syncthreads();
  const int d = blockIdx.y * 4 + ty;
  const float* row = R + (size_t)d * N_REF;
  const float sum = row[ids[tx][0]] + row[ids[tx][1]] + row[ids[tx][2]] + row[ids[tx][3]];
  out[(size_t)d * T_Q + t0 + tx] = 0.25f * sum;
}

#define FBM 64
#define FBN 256
#define FBK 16
#define FNL (N_REF / FBN)
__global__ __launch_bounds__(256)
void score_topk_kernel(const float* __restrict__ X, const float* __restrict__ R,
                       const float* __restrict__ r2,
                       float* __restrict__ pscore, int* __restrict__ pidx) {
  __shared__ float As[FBK][FBM];
  __shared__ float Bs[FBK][FBN];
  __shared__ float r2s[FBN];
  const int tid = threadIdx.x;
  const int tx = tid & 15, ty = tid >> 4;
  const int m0 = blockIdx.y * FBM;
  const int n0 = blockIdx.x * FBN;
  r2s[tid] = r2[n0 + tid];
  float acc[4][16];
#pragma unroll
  for (int i = 0; i < 4; ++i)
#pragma unroll
    for (int j = 0; j < 16; ++j) acc[i][j] = 0.f;
  for (int k0 = 0; k0 < DIM; k0 += FBK) {
    {
      const int k = tid >> 4, m4 = tid & 15;
      const float4 av = *(const float4*)&X[(size_t)(k0 + k) * T_Q + m0 + m4 * 4];
      *(float4*)&As[k][m4 * 4] = av;
    }
#pragma unroll
    for (int i = 0; i < 4; ++i) {
      const int idx4 = tid + i * 256;
      const int k = idx4 >> 6, n4 = idx4 & 63;
      const float4 bv = *(const float4*)&R[(size_t)(k0 + k) * N_REF + n0 + n4 * 4];
      *(float4*)&Bs[k][n4 * 4] = bv;
    }
    __syncthreads();
#pragma unroll
    for (int k = 0; k < FBK; ++k) {
      float av[4], bv[16];
      *(float4*)av = *(const float4*)&As[k][ty * 4];
#pragma unroll
      for (int c = 0; c < 4; ++c)
        *(float4*)&bv[c * 4] = *(const float4*)&Bs[k][tx * 4 + c * 64];
#pragma unroll
      for (int mi = 0; mi < 4; ++mi)
#pragma unroll
        for (int ni = 0; ni < 16; ++ni) acc[mi][ni] += av[mi] * bv[ni];
    }
    __syncthreads();
  }
#pragma unroll
  for (int mi = 0; mi < 4; ++mi) {
    float s[4]  = {1e30f, 1e30f, 1e30f, 1e30f};
    int   id[4] = {0x7fffffff, 0x7fffffff, 0x7fffffff, 0x7fffffff};
#pragma unroll
    for (int c = 0; c < 4; ++c)
#pragma unroll
      for (int j = 0; j < 4; ++j) {
        const int nl = tx * 4 + c * 64 + j;
        const float sc = r2s[nl] - 2.0f * acc[mi][c * 4 + j];
        insert4(s, id, sc, n0 + nl);
      }
#pragma unroll
    for (int mask = 1; mask < 16; mask <<= 1) {
      float os[4]; int oid[4];
#pragma unroll
      for (int j = 0; j < 4; ++j) {
        os[j]  = __shfl_xor(s[j], mask);
        oid[j] = __shfl_xor(id[j], mask);
      }
      merge_top4(s, id, os, oid);
    }
    if (tx == 0) {
      const int t = m0 + ty * 4 + mi;
      const int base = (t * FNL + (int)blockIdx.x) * 4;
#pragma unroll
      for (int j = 0; j < 4; ++j) { pscore[base + j] = s[j]; pidx[base + j] = id[j]; }
    }
  }
}

template <int NLISTS>
__global__ __launch_bounds__(64)
void select_kernel(const float* __restrict__ pscore, const int* __restrict__ pidx,
                   int* __restrict__ final4) {
  const int t = blockIdx.x, lane = threadIdx.x;
  constexpr int LPL = NLISTS / 64;
  float s[4]  = {1e30f, 1e30f, 1e30f, 1e30f};
  int   id[4] = {0x7fffffff, 0x7fffffff, 0x7fffffff, 0x7fffffff};
#pragma unroll
  for (int li = 0; li < LPL; ++li) {
    const int base = (t * NLISTS + lane * LPL + li) * 4;
    const float4 sv = *(const float4*)&pscore[base];
    const int4   iv = *(const int4*)&pidx[base];
    float os[4] = {sv.x, sv.y, sv.z, sv.w};
    int  oid[4] = {iv.x, iv.y, iv.z, iv.w};
    merge_top4(s, id, os, oid);
  }
#pragma unroll
  for (int mask = 1; mask < 64; mask <<= 1) {
    float os[4]; int oid[4];
#pragma unroll
    for (int j = 0; j < 4; ++j) {
      os[j]  = __shfl_xor(s[j], mask);
      oid[j] = __shfl_xor(id[j], mask);
    }
    merge_top4(s, id, os, oid);
  }
  if (lane == 0) {
    int4 o; o.x = id[0]; o.y = id[1]; o.z = id[2]; o.w = id[3];
    *(int4*)&final4[t * 4] = o;
  }
}

extern "C" void kernel_launch(void* const* d_in, const int* in_sizes, int n_in,
                              void* d_out, int out_size, void* d_ws, size_t ws_size,
                              hipStream_t stream) {
  const float* X = (const float*)d_in[0];   // [768][2048]
  const float* R = (const float*)d_in[1];   // [768][16384]
  float* out = (float*)d_out;               // [768][2048]

  const size_t szA2 = (size_t)T_Q * KP2 * sizeof(f16);        // 6,291,456
  const size_t szB2 = (size_t)N_REF * KP2 * sizeof(f16);      // 50,331,648
  const size_t szRP = (size_t)NDB * N_REF * sizeof(float);    // 786,432
  const size_t szr2 = (size_t)N_REF * sizeof(float);          // 65,536
  const size_t szPL = (size_t)T_Q * NL * 4 * sizeof(u64);     // 8,388,608
  const size_t need = szA2 + szB2 + szRP + szr2 + szPL +
                      (size_t)T_Q * 4 * sizeof(int);

  if (ws_size >= need) {
    char* w = (char*)d_ws;
    f16* A2 = (f16*)w;            w += szA2;
    f16* B2 = (f16*)w;            w += szB2;
    float* r2p    = (float*)w;    w += szRP;
    float* r2     = (float*)w;    w += szr2;
    u64*   plist  = (u64*)w;      w += szPL;
    int*   final4 = (int*)w;

    hipLaunchKernelGGL(tsplit2_kernel, dim3(T_Q / 64 + N_REF / 64, NDB), dim3(256), 0,
                       stream, X, R, A2, B2, r2p);
    hipLaunchKernelGGL(r2sum_kernel, dim3(N_REF / 256), dim3(256), 0, stream, r2p, r2);
    hipLaunchKernelGGL(mfma128_topk_kernel, dim3((N_REF / 128) * (T_Q / 128)), dim3(256), 0,
                       stream, A2, B2, r2, plist);
    hipLaunchKernelGGL(selres_kernel, dim3(T_Q), dim3(512), 0, stream,
                       plist, A2, B2, r2, final4);
    hipLaunchKernelGGL(gatherB2_kernel, dim3(T_Q / 64, DIM / 64), dim3(256), 0, stream,
                       B2, final4, out);
  } else {
    // fallback: fp32 pipeline (~4.2 MB ws)
    char* w = (char*)d_ws;
    float* r2     = (float*)w;  w += szr2;
    float* pscore = (float*)w;  w += (size_t)T_Q * FNL * 4 * sizeof(float);
    int*   pidx   = (int*)w;    w += (size_t)T_Q * FNL * 4 * sizeof(int);
    int*   final4 = (int*)w;

    hipLaunchKernelGGL(r2_kernel, dim3(N_REF / 64), dim3(256), 0, stream, R, r2);
    hipLaunchKernelGGL(score_topk_kernel, dim3(N_REF / FBN, T_Q / FBM), dim3(256), 0, stream,
                       X, R, r2, pscore, pidx);
    hipLaunchKernelGGL((select_kernel<FNL>), dim3(T_Q), dim3(64), 0, stream,
                       pscore, pidx, final4);
    hipLaunchKernelGGL(gather_kernel, dim3(T_Q / 64, DIM / 4), dim3(256), 0, stream,
                       R, final4, out);
  }
}

// Round 18
// 134.153 us; speedup vs baseline: 1.2039x; 1.0071x over previous
//
#include <hip/hip_runtime.h>
#include <stdint.h>

#define T_Q   2048
#define N_REF 16384
#define DIM   768
#define KP2   1536        // packed K cols: [hi | lo]
#define NT    24          // K = 768 = 24 tiles of 32 (hi limb only)
#define NL    128         // partial top-4 lists per query (128-col block stripes)
#define NDB   (DIM / 64)  // 12 d-blocks for partial r2

using f16   = _Float16;
using f16x4 = __attribute__((ext_vector_type(4))) _Float16;
using f16x8 = __attribute__((ext_vector_type(8))) _Float16;
using f32x4 = __attribute__((ext_vector_type(4))) float;
typedef unsigned long long u64;

// ---------- exact-path lexicographic top-4 (float score, int idx) ----------
__device__ __forceinline__ bool lex_less(float sa, int ia, float sb, int ib) {
  return (sa < sb) || (sa == sb && ia < ib);
}
#define CE_PAIR(s0, i0, s1, i1)                                        \
  { if (lex_less(s1, i1, s0, i0)) { float _ts = s0; s0 = s1; s1 = _ts; \
                                    int _ti = i0; i0 = i1; i1 = _ti; } }
#define PICKMIN(as, ai, bs, bi, rs, ri)                   \
  { if (lex_less(bs, bi, as, ai)) { rs = bs; ri = bi; }   \
    else                          { rs = as; ri = ai; } }

__device__ __forceinline__ void insert4(float s[4], int id[4], float sc, int n) {
  if (lex_less(sc, n, s[3], id[3])) {
    s[3] = sc; id[3] = n;
    CE_PAIR(s[2], id[2], s[3], id[3]);
    CE_PAIR(s[1], id[1], s[2], id[2]);
    CE_PAIR(s[0], id[0], s[1], id[1]);
  }
}
__device__ __forceinline__ void merge_top4(float s[4], int id[4],
                                           const float os[4], const int oid[4]) {
  float l0, l1, l2, l3; int j0, j1, j2, j3;
  PICKMIN(s[0], id[0], os[3], oid[3], l0, j0);
  PICKMIN(s[1], id[1], os[2], oid[2], l1, j1);
  PICKMIN(s[2], id[2], os[1], oid[1], l2, j2);
  PICKMIN(s[3], id[3], os[0], oid[0], l3, j3);
  CE_PAIR(l0, j0, l2, j2);
  CE_PAIR(l1, j1, l3, j3);
  CE_PAIR(l0, j0, l1, j1);
  CE_PAIR(l2, j2, l3, j3);
  s[0] = l0; s[1] = l1; s[2] = l2; s[3] = l3;
  id[0] = j0; id[1] = j1; id[2] = j2; id[3] = j3;
}

// ---------- packed-u64 ranking: (sortable_score32 << 32) | col ----------
__device__ __forceinline__ uint32_t fsort32(float f) {
  uint32_t u = __float_as_uint(f);
  return ((int)u < 0) ? ~u : (u | 0x80000000u);
}
__device__ __forceinline__ void ins4u(u64 s[4], u64 c) {
  if (c < s[3]) {
    s[3] = c;
    if (s[3] < s[2]) { u64 t = s[2]; s[2] = s[3]; s[3] = t; }
    if (s[2] < s[1]) { u64 t = s[1]; s[1] = s[2]; s[2] = t; }
    if (s[1] < s[0]) { u64 t = s[0]; s[0] = s[1]; s[1] = t; }
  }
}
#define CEU(a, b) { u64 _mn = (a) < (b) ? (a) : (b); \
                    u64 _mx = (a) < (b) ? (b) : (a); (a) = _mn; (b) = _mx; }
__device__ __forceinline__ void merge4u(u64 s[4], const u64 o[4]) {
  u64 l0 = s[0] < o[3] ? s[0] : o[3];
  u64 l1 = s[1] < o[2] ? s[1] : o[2];
  u64 l2 = s[2] < o[1] ? s[2] : o[1];
  u64 l3 = s[3] < o[0] ? s[3] : o[0];
  CEU(l0, l2); CEU(l1, l3); CEU(l0, l1); CEU(l2, l3);
  s[0] = l0; s[1] = l1; s[2] = l2; s[3] = l3;
}
__device__ __forceinline__ void merge8u(u64 s[8], const u64 o[8]) {
  u64 l0 = s[0] < o[7] ? s[0] : o[7];
  u64 l1 = s[1] < o[6] ? s[1] : o[6];
  u64 l2 = s[2] < o[5] ? s[2] : o[5];
  u64 l3 = s[3] < o[4] ? s[3] : o[4];
  u64 l4 = s[4] < o[3] ? s[4] : o[3];
  u64 l5 = s[5] < o[2] ? s[5] : o[2];
  u64 l6 = s[6] < o[1] ? s[6] : o[1];
  u64 l7 = s[7] < o[0] ? s[7] : o[0];
  CEU(l0, l4); CEU(l1, l5); CEU(l2, l6); CEU(l3, l7);
  CEU(l0, l2); CEU(l1, l3); CEU(l4, l6); CEU(l5, l7);
  CEU(l0, l1); CEU(l2, l3); CEU(l4, l5); CEU(l6, l7);
  s[0]=l0; s[1]=l1; s[2]=l2; s[3]=l3; s[4]=l4; s[5]=l5; s[6]=l6; s[7]=l7;
}

__device__ __forceinline__ void gl_lds16(const void* g, void* l) {
  __builtin_amdgcn_global_load_lds((const __attribute__((address_space(1))) uint32_t*)g,
                                   (__attribute__((address_space(3))) uint32_t*)l, 16, 0, 0);
}

// ---------- fused transpose + f16 hi/lo split for X AND R (+ partial r2) ----------
__global__ __launch_bounds__(256)
void tsplit2_kernel(const float* __restrict__ X, const float* __restrict__ R,
                    f16* __restrict__ A2, f16* __restrict__ B2,
                    float* __restrict__ r2p) {
  __shared__ f16 lh[64][66], ll[64][66];
  const int bxg = (int)blockIdx.x;
  const bool isX = bxg < (T_Q / 64);
  const float* in = isX ? X : R;
  const int W = isX ? T_Q : N_REF;
  f16* out = isX ? A2 : B2;
  const int c0 = (isX ? bxg : bxg - T_Q / 64) * 64;
  const int d0 = blockIdx.y * 64;
  const int q = threadIdx.x & 15, p = threadIdx.x >> 4;
  float a0 = 0.f, a1 = 0.f, a2 = 0.f, a3 = 0.f;
#pragma unroll
  for (int i = 0; i < 4; ++i) {
    const int dl = p + i * 16;
    const float4 v = *(const float4*)&in[(size_t)(d0 + dl) * W + c0 + q * 4];
    const f16 h0 = (f16)v.x, h1 = (f16)v.y, h2 = (f16)v.z, h3 = (f16)v.w;
    lh[q * 4 + 0][dl] = h0; ll[q * 4 + 0][dl] = (f16)(v.x - (float)h0);
    lh[q * 4 + 1][dl] = h1; ll[q * 4 + 1][dl] = (f16)(v.y - (float)h1);
    lh[q * 4 + 2][dl] = h2; ll[q * 4 + 2][dl] = (f16)(v.z - (float)h2);
    lh[q * 4 + 3][dl] = h3; ll[q * 4 + 3][dl] = (f16)(v.w - (float)h3);
    a0 = fmaf(v.x, v.x, a0); a1 = fmaf(v.y, v.y, a1);
    a2 = fmaf(v.z, v.z, a2); a3 = fmaf(v.w, v.w, a3);
  }
  __syncthreads();
  const int rl = threadIdx.x >> 2, seg = threadIdx.x & 3;
  f16* rowo = out + (size_t)(c0 + rl) * KP2 + d0;
#pragma unroll
  for (int j = 0; j < 4; ++j) {
    const int dd = seg * 16 + j * 4;
    f16x4 vh = *(const f16x4*)&lh[rl][dd];
    f16x4 vl = *(const f16x4*)&ll[rl][dd];
    *(f16x4*)&rowo[dd] = vh;
    *(f16x4*)&rowo[768 + dd] = vl;
  }
  if (!isX) {
    __syncthreads();
    float* sq = (float*)lh;   // 16 x 64 f32 = 4 KB
    sq[p * 64 + q * 4 + 0] = a0;
    sq[p * 64 + q * 4 + 1] = a1;
    sq[p * 64 + q * 4 + 2] = a2;
    sq[p * 64 + q * 4 + 3] = a3;
    __syncthreads();
    if (threadIdx.x < 64) {
      float s = 0.f;
#pragma unroll
      for (int pp = 0; pp < 16; ++pp) s += sq[pp * 64 + threadIdx.x];
      r2p[(size_t)blockIdx.y * N_REF + c0 + threadIdx.x] = s;
    }
  }
}

// ---------- sum 12 partials -> r2 (deterministic fixed order, ~2 us) ----------
__global__ __launch_bounds__(256)
void r2sum_kernel(const float* __restrict__ r2p, float* __restrict__ r2) {
  const int t = blockIdx.x * 256 + threadIdx.x;
  float s = 0.f;
#pragma unroll
  for (int k = 0; k < NDB; ++k) s += r2p[(size_t)k * N_REF + t];
  r2[t] = s;
}

// ---------- 128x128 f16-hi MFMA GEMM, 3-buf depth-2, ONE barrier/tile ----------
// Ledger: per tile {vmcnt(4) retires THIS tile's loads (issued 2 tiles ago) ->
// s_barrier (collective) -> STAGE T+2 into buf((kt+2)%3) (its tile-(kt-1)
// readers drained before this barrier) -> 8 ds_reads -> MFMA}. 24 barriers
// (was 48), depth-2 prefetch. LDS 48 KB -> 3 blocks/CU (unchanged).
__global__ __launch_bounds__(256, 2)
void mfma128_topk_kernel(const f16* __restrict__ A2, const f16* __restrict__ B2,
                         const float* __restrict__ r2g, u64* __restrict__ plist) {
  __shared__ __align__(16) char smem[49152];
  const int tid  = threadIdx.x;
  const int lane = tid & 63, wid = tid >> 6;
  const int wm = wid >> 1, wn = wid & 1;
  const int ln15 = lane & 15, g4 = lane >> 4;

  const int flat = (int)blockIdx.x;
  const int jj = flat >> 3;
  const int bx = (flat & 7) * 16 + (jj & 15);  // 0..127
  const int by = jj >> 4;                      // 0..15
  const int m0 = by * 128, n0 = bx * 128;

  const int s0 = tid, s1 = tid + 256;
  const int r0 = s0 >> 2, r1 = s1 >> 2;
  const int c0b = (((s0 & 3) ^ ((s0 >> 3) & 3)) << 4);
  const int c1b = (((s1 & 3) ^ ((s1 >> 3) & 3)) << 4);
  const char* gA0 = (const char*)(A2 + (size_t)(m0 + r0) * KP2) + c0b;
  const char* gA1 = (const char*)(A2 + (size_t)(m0 + r1) * KP2) + c1b;
  const char* gB0 = (const char*)(B2 + (size_t)(n0 + r0) * KP2) + c0b;
  const char* gB1 = (const char*)(B2 + (size_t)(n0 + r1) * KP2) + c1b;
  const int l0 = s0 * 16, l1 = s1 * 16;

#define STAGE_A(bufo, kbyte)                                     \
  { gl_lds16(gA0 + (kbyte), smem + (bufo) + l0);                 \
    gl_lds16(gA1 + (kbyte), smem + (bufo) + l1); }
#define STAGE_B(bufo, kbyte)                                     \
  { gl_lds16(gB0 + (kbyte), smem + (bufo) + 8192 + l0);          \
    gl_lds16(gB1 + (kbyte), smem + (bufo) + 8192 + l1); }

  const int cswz = ((g4 ^ ((ln15 >> 1) & 3)) << 4);
  int offA[4], offB[4];
#pragma unroll
  for (int mi = 0; mi < 4; ++mi) offA[mi] = (wm * 64 + mi * 16 + ln15) * 64 + cswz;
#pragma unroll
  for (int ni = 0; ni < 4; ++ni) offB[ni] = 8192 + (wn * 64 + ni * 16 + ln15) * 64 + cswz;

  f32x4 acc[4][4] = {};

  // prologue: stage tiles 0,1 into bufs 0,1 (8 loads outstanding)
  STAGE_A(0, 0);
  STAGE_B(0, 0);
  STAGE_A(16384, 64);
  STAGE_B(16384, 64);

  // one K-step; DB/SB are compile-time buffer byte offsets (kt%3, (kt+2)%3)
#define KSTEP(KT, DB, SB)                                                      \
  {                                                                            \
    asm volatile("s_waitcnt vmcnt(4)" ::: "memory");                           \
    asm volatile("s_barrier" ::: "memory");                                    \
    const int ktn = ((KT) + 2 < NT) ? (KT) + 2 : NT - 1;                       \
    STAGE_A(SB, ktn * 64);                                                     \
    STAGE_B(SB, ktn * 64);                                                     \
    f16x8 a[4], b[4];                                                          \
    a[0] = *(const f16x8*)(smem + (DB) + offA[0]);                             \
    b[0] = *(const f16x8*)(smem + (DB) + offB[0]);                             \
    a[1] = *(const f16x8*)(smem + (DB) + offA[1]);                             \
    b[1] = *(const f16x8*)(smem + (DB) + offB[1]);                             \
    a[2] = *(const f16x8*)(smem + (DB) + offA[2]);                             \
    b[2] = *(const f16x8*)(smem + (DB) + offB[2]);                             \
    a[3] = *(const f16x8*)(smem + (DB) + offA[3]);                             \
    b[3] = *(const f16x8*)(smem + (DB) + offB[3]);                             \
    __builtin_amdgcn_s_setprio(1);                                             \
    _Pragma("unroll")                                                          \
    for (int mi = 0; mi < 4; ++mi)                                             \
      _Pragma("unroll")                                                        \
      for (int ni = 0; ni < 4; ++ni)                                           \
        acc[mi][ni] = __builtin_amdgcn_mfma_f32_16x16x32_f16(a[mi], b[ni],     \
                                                             acc[mi][ni], 0, 0, 0); \
    __builtin_amdgcn_s_setprio(0);                                             \
  }

#pragma unroll
  for (int kb = 0; kb < NT; kb += 3) {
    KSTEP(kb + 0, 0, 32768);
    KSTEP(kb + 1, 16384, 0);
    KSTEP(kb + 2, 32768, 16384);
  }
#undef KSTEP

  asm volatile("s_waitcnt vmcnt(0)" ::: "memory");
  __syncthreads();

  // ---- epilogue: scatter sortable-u32, per-row u64 top-4 per 64-col stripe ----
  float rv[4];
#pragma unroll
  for (int ni = 0; ni < 4; ++ni) rv[ni] = r2g[n0 + wn * 64 + ni * 16 + ln15];
  uint32_t* swu = (uint32_t*)smem + wid * 2112;   // [32][66] u32, wave-private
  const int rr = lane >> 1, hh = lane & 1;
  u64 keep[2][4];
#pragma unroll
  for (int P = 0; P < 2; ++P) {
#pragma unroll
    for (int mh = 0; mh < 2; ++mh)
#pragma unroll
      for (int ni = 0; ni < 4; ++ni)
#pragma unroll
        for (int r = 0; r < 4; ++r) {
          const int row_l = mh * 16 + g4 * 4 + r;   // C/D: col=lane&15, row=(lane>>4)*4+reg
          swu[row_l * 66 + ni * 16 + ln15] = fsort32(rv[ni] - 2.0f * acc[2 * P + mh][ni][r]);
        }
    asm volatile("s_waitcnt lgkmcnt(0)" ::: "memory");
    __builtin_amdgcn_sched_barrier(0);
    u64 s[4] = {~0ull, ~0ull, ~0ull, ~0ull};
    const uint32_t* rowp = swu + rr * 66 + hh * 32;
    const uint32_t cb = (uint32_t)(n0 + wn * 64 + hh * 32);
#pragma unroll
    for (int j = 0; j < 16; ++j) {
      const uint2 v = *(const uint2*)(rowp + j * 2);
      ins4u(s, ((u64)v.x << 32) | (cb + j * 2));
      ins4u(s, ((u64)v.y << 32) | (cb + j * 2 + 1));
    }
    u64 os[4];
#pragma unroll
    for (int j = 0; j < 4; ++j) os[j] = __shfl_xor((u64)s[j], 1);
    merge4u(s, os);
#pragma unroll
    for (int j = 0; j < 4; ++j) keep[P][j] = s[j];
    asm volatile("s_waitcnt lgkmcnt(0)" ::: "memory");
  }

  // ---- cross-wn merge: one 4-list per query row per block (NL = 128) ----
  __syncthreads();
  u64* lbuf = (u64*)smem;               // [128 rows][4] u64 = 4 KB
  if (wn == 1 && hh == 0) {
#pragma unroll
    for (int P = 0; P < 2; ++P) {
      const int lrow = wm * 64 + P * 32 + rr;
#pragma unroll
      for (int j = 0; j < 4; ++j) lbuf[lrow * 4 + j] = keep[P][j];
    }
  }
  __syncthreads();
  if (wn == 0 && hh == 0) {
#pragma unroll
    for (int P = 0; P < 2; ++P) {
      const int lrow = wm * 64 + P * 32 + rr;
      u64 o[4];
#pragma unroll
      for (int j = 0; j < 4; ++j) o[j] = lbuf[lrow * 4 + j];
      merge4u(keep[P], o);
      u64* dst = plist + ((size_t)(m0 + lrow) * NL + bx) * 4;
#pragma unroll
      for (int j = 0; j < 4; ++j) dst[j] = keep[P][j];
    }
  }
#undef STAGE_A
#undef STAGE_B
}

// ---------- fused select+rescore: 8 waves, wave w rescores candidate w ----------
__global__ __launch_bounds__(512)
void selres_kernel(const u64* __restrict__ plist,
                   const f16* __restrict__ A2, const f16* __restrict__ B2,
                   const float* __restrict__ r2, int* __restrict__ final4) {
  const int t = blockIdx.x;
  const int lane = threadIdx.x & 63, wid = threadIdx.x >> 6;
  __shared__ int cids[8];
  __shared__ float scs[8];

  if (wid == 0) {
    u64 s[8];
#pragma unroll
    for (int j = 0; j < 8; ++j) s[j] = ~0ull;
#pragma unroll
    for (int li = 0; li < 2; ++li) {
      const u64* src = plist + ((size_t)t * NL + lane * 2 + li) * 4;
      u64 o[8] = {src[0], src[1], src[2], src[3], ~0ull, ~0ull, ~0ull, ~0ull};
      merge8u(s, o);
    }
#pragma unroll
    for (int mask = 1; mask < 64; mask <<= 1) {
      u64 o[8];
#pragma unroll
      for (int j = 0; j < 8; ++j) o[j] = __shfl_xor((u64)s[j], mask);
      merge8u(s, o);
    }
    if (lane == 0) {
#pragma unroll
      for (int j = 0; j < 8; ++j) cids[j] = (int)(uint32_t)s[j];
    }
  }
  __syncthreads();

  const int cid = cids[wid];
  const f16* xrow = A2 + (size_t)t * KP2;
  const f16* rrow = B2 + (size_t)cid * KP2;
  float acc = 0.f;
#pragma unroll
  for (int k = 0; k < 12; ++k) {
    const float xhv = (float)xrow[lane + 64 * k];
    const float xlv = (float)xrow[768 + lane + 64 * k];
    const float rh = (float)rrow[lane + 64 * k];
    const float rl = (float)rrow[768 + lane + 64 * k];
    acc = fmaf(xhv, rh, acc);
    acc = fmaf(xhv, rl, acc);
    acc = fmaf(xlv, rh, acc);
  }
#pragma unroll
  for (int m = 1; m < 64; m <<= 1) acc += __shfl_xor(acc, m);
  if (lane == 0) scs[wid] = r2[cid] - 2.0f * acc;
  __syncthreads();

  if (threadIdx.x == 0) {
    float s4[4] = {1e30f, 1e30f, 1e30f, 1e30f};
    int   i4[4] = {0x7fffffff, 0x7fffffff, 0x7fffffff, 0x7fffffff};
#pragma unroll
    for (int j = 0; j < 8; ++j) insert4(s4, i4, scs[j], cids[j]);
    int4 o; o.x = i4[0]; o.y = i4[1]; o.z = i4[2]; o.w = i4[3];
    *(int4*)&final4[t * 4] = o;
  }
}

// ---------- gather from B2 rows (coalesced) + LDS transpose -> out [d][T] ----------
__global__ __launch_bounds__(256)
void gatherB2_kernel(const f16* __restrict__ B2, const int* __restrict__ final4,
                     float* __restrict__ out) {
  __shared__ int ids[64][4];
  __shared__ float tr[64][65];
  const int tid = threadIdx.x;
  const int t0 = blockIdx.x * 64;
  const int d0 = blockIdx.y * 64;
  ((int*)ids)[tid] = final4[t0 * 4 + tid];
  __syncthreads();

  const int q = tid >> 2, dp = tid & 3;   // query q, d-span dp*16..+16
  float a[16];
#pragma unroll
  for (int k = 0; k < 16; ++k) a[k] = 0.f;
#pragma unroll
  for (int j = 0; j < 4; ++j) {
    const f16* row = B2 + (size_t)ids[q][j] * KP2 + d0 + dp * 16;
#pragma unroll
    for (int v = 0; v < 2; ++v) {
      const f16x8 h = *(const f16x8*)(row + v * 8);
      const f16x8 l = *(const f16x8*)(row + 768 + v * 8);
#pragma unroll
      for (int e = 0; e < 8; ++e) a[v * 8 + e] += (float)h[e] + (float)l[e];
    }
  }
#pragma unroll
  for (int k = 0; k < 16; ++k) tr[q][dp * 16 + k] = 0.25f * a[k];
  __syncthreads();

  const int dd = tid >> 2, seg = tid & 3;
  float* orow = out + (size_t)(d0 + dd) * T_Q + t0 + seg * 16;
#pragma unroll
  for (int k = 0; k < 4; ++k) {
    float4 v4;
    v4.x = tr[seg * 16 + k * 4 + 0][dd];
    v4.y = tr[seg * 16 + k * 4 + 1][dd];
    v4.z = tr[seg * 16 + k * 4 + 2][dd];
    v4.w = tr[seg * 16 + k * 4 + 3][dd];
    *(float4*)(orow + k * 4) = v4;
  }
}

// ---------- fallback fp32 pipeline (round-1, known correct) ----------
__global__ __launch_bounds__(256)
void r2_kernel(const float* __restrict__ R, float* __restrict__ r2) {
  __shared__ float red[256];
  const int lane = threadIdx.x & 63;
  const int dg   = threadIdx.x >> 6;
  const int n    = blockIdx.x * 64 + lane;
  float acc = 0.f;
  const int d0 = dg * (DIM / 4), d1 = d0 + (DIM / 4);
  for (int d = d0; d < d1; ++d) {
    float v = R[(size_t)d * N_REF + n];
    acc += v * v;
  }
  red[threadIdx.x] = acc;
  __syncthreads();
  if (threadIdx.x < 64)
    r2[n] = red[lane] + red[lane + 64] + red[lane + 128] + red[lane + 192];
}

__global__ __launch_bounds__(256)
void gather_kernel(const float* __restrict__ R, const int* __restrict__ final4,
                   float* __restrict__ out) {
  __shared__ int ids[64][4];
  const int tx = threadIdx.x & 63, ty = threadIdx.x >> 6;
  const int t0 = blockIdx.x * 64;
  ((int*)ids)[threadIdx.x] = final4[t0 * 4 + threadIdx.x];
  __syncthreads();
  const int d = blockIdx.y * 4 + ty;
  const float* row = R + (size_t)d * N_REF;
  const float sum = row[ids[tx][0]] + row[ids[tx][1]] + row[ids[tx][2]] + row[ids[tx][3]];
  out[(size_t)d * T_Q + t0 + tx] = 0.25f * sum;
}

#define FBM 64
#define FBN 256
#define FBK 16
#define FNL (N_REF / FBN)
__global__ __launch_bounds__(256)
void score_topk_kernel(const float* __restrict__ X, const float* __restrict__ R,
                       const float* __restrict__ r2,
                       float* __restrict__ pscore, int* __restrict__ pidx) {
  __shared__ float As[FBK][FBM];
  __shared__ float Bs[FBK][FBN];
  __shared__ float r2s[FBN];
  const int tid = threadIdx.x;
  const int tx = tid & 15, ty = tid >> 4;
  const int m0 = blockIdx.y * FBM;
  const int n0 = blockIdx.x * FBN;
  r2s[tid] = r2[n0 + tid];
  float acc[4][16];
#pragma unroll
  for (int i = 0; i < 4; ++i)
#pragma unroll
    for (int j = 0; j < 16; ++j) acc[i][j] = 0.f;
  for (int k0 = 0; k0 < DIM; k0 += FBK) {
    {
      const int k = tid >> 4, m4 = tid & 15;
      const float4 av = *(const float4*)&X[(size_t)(k0 + k) * T_Q + m0 + m4 * 4];
      *(float4*)&As[k][m4 * 4] = av;
    }
#pragma unroll
    for (int i = 0; i < 4; ++i) {
      const int idx4 = tid + i * 256;
      const int k = idx4 >> 6, n4 = idx4 & 63;
      const float4 bv = *(const float4*)&R[(size_t)(k0 + k) * N_REF + n0 + n4 * 4];
      *(float4*)&Bs[k][n4 * 4] = bv;
    }
    __syncthreads();
#pragma unroll
    for (int k = 0; k < FBK; ++k) {
      float av[4], bv[16];
      *(float4*)av = *(const float4*)&As[k][ty * 4];
#pragma unroll
      for (int c = 0; c < 4; ++c)
        *(float4*)&bv[c * 4] = *(const float4*)&Bs[k][tx * 4 + c * 64];
#pragma unroll
      for (int mi = 0; mi < 4; ++mi)
#pragma unroll
        for (int ni = 0; ni < 16; ++ni) acc[mi][ni] += av[mi] * bv[ni];
    }
    __syncthreads();
  }
#pragma unroll
  for (int mi = 0; mi < 4; ++mi) {
    float s[4]  = {1e30f, 1e30f, 1e30f, 1e30f};
    int   id[4] = {0x7fffffff, 0x7fffffff, 0x7fffffff, 0x7fffffff};
#pragma unroll
    for (int c = 0; c < 4; ++c)
#pragma unroll
      for (int j = 0; j < 4; ++j) {
        const int nl = tx * 4 + c * 64 + j;
        const float sc = r2s[nl] - 2.0f * acc[mi][c * 4 + j];
        insert4(s, id, sc, n0 + nl);
      }
#pragma unroll
    for (int mask = 1; mask < 16; mask <<= 1) {
      float os[4]; int oid[4];
#pragma unroll
      for (int j = 0; j < 4; ++j) {
        os[j]  = __shfl_xor(s[j], mask);
        oid[j] = __shfl_xor(id[j], mask);
      }
      merge_top4(s, id, os, oid);
    }
    if (tx == 0) {
      const int t = m0 + ty * 4 + mi;
      const int base = (t * FNL + (int)blockIdx.x) * 4;
#pragma unroll
      for (int j = 0; j < 4; ++j) { pscore[base + j] = s[j]; pidx[base + j] = id[j]; }
    }
  }
}

template <int NLISTS>
__global__ __launch_bounds__(64)
void select_kernel(const float* __restrict__ pscore, const int* __restrict__ pidx,
                   int* __restrict__ final4) {
  const int t = blockIdx.x, lane = threadIdx.x;
  constexpr int LPL = NLISTS / 64;
  float s[4]  = {1e30f, 1e30f, 1e30f, 1e30f};
  int   id[4] = {0x7fffffff, 0x7fffffff, 0x7fffffff, 0x7fffffff};
#pragma unroll
  for (int li = 0; li < LPL; ++li) {
    const int base = (t * NLISTS + lane * LPL + li) * 4;
    const float4 sv = *(const float4*)&pscore[base];
    const int4   iv = *(const int4*)&pidx[base];
    float os[4] = {sv.x, sv.y, sv.z, sv.w};
    int  oid[4] = {iv.x, iv.y, iv.z, iv.w};
    merge_top4(s, id, os, oid);
  }
#pragma unroll
  for (int mask = 1; mask < 64; mask <<= 1) {
    float os[4]; int oid[4];
#pragma unroll
    for (int j = 0; j < 4; ++j) {
      os[j]  = __shfl_xor(s[j], mask);
      oid[j] = __shfl_xor(id[j], mask);
    }
    merge_top4(s, id, os, oid);
  }
  if (lane == 0) {
    int4 o; o.x = id[0]; o.y = id[1]; o.z = id[2]; o.w = id[3];
    *(int4*)&final4[t * 4] = o;
  }
}

extern "C" void kernel_launch(void* const* d_in, const int* in_sizes, int n_in,
                              void* d_out, int out_size, void* d_ws, size_t ws_size,
                              hipStream_t stream) {
  const float* X = (const float*)d_in[0];   // [768][2048]
  const float* R = (const float*)d_in[1];   // [768][16384]
  float* out = (float*)d_out;               // [768][2048]

  const size_t szA2 = (size_t)T_Q * KP2 * sizeof(f16);        // 6,291,456
  const size_t szB2 = (size_t)N_REF * KP2 * sizeof(f16);      // 50,331,648
  const size_t szRP = (size_t)NDB * N_REF * sizeof(float);    // 786,432
  const size_t szr2 = (size_t)N_REF * sizeof(float);          // 65,536
  const size_t szPL = (size_t)T_Q * NL * 4 * sizeof(u64);     // 8,388,608
  const size_t need = szA2 + szB2 + szRP + szr2 + szPL +
                      (size_t)T_Q * 4 * sizeof(int);

  if (ws_size >= need) {
    char* w = (char*)d_ws;
    f16* A2 = (f16*)w;            w += szA2;
    f16* B2 = (f16*)w;            w += szB2;
    float* r2p    = (float*)w;    w += szRP;
    float* r2     = (float*)w;    w += szr2;
    u64*   plist  = (u64*)w;      w += szPL;
    int*   final4 = (int*)w;

    hipLaunchKernelGGL(tsplit2_kernel, dim3(T_Q / 64 + N_REF / 64, NDB), dim3(256), 0,
                       stream, X, R, A2, B2, r2p);
    hipLaunchKernelGGL(r2sum_kernel, dim3(N_REF / 256), dim3(256), 0, stream, r2p, r2);
    hipLaunchKernelGGL(mfma128_topk_kernel, dim3((N_REF / 128) * (T_Q / 128)), dim3(256), 0,
                       stream, A2, B2, r2, plist);
    hipLaunchKernelGGL(selres_kernel, dim3(T_Q), dim3(512), 0, stream,
                       plist, A2, B2, r2, final4);
    hipLaunchKernelGGL(gatherB2_kernel, dim3(T_Q / 64, DIM / 64), dim3(256), 0, stream,
                       B2, final4, out);
  } else {
    // fallback: fp32 pipeline (~4.2 MB ws)
    char* w = (char*)d_ws;
    float* r2     = (float*)w;  w += szr2;
    float* pscore = (float*)w;  w += (size_t)T_Q * FNL * 4 * sizeof(float);
    int*   pidx   = (int*)w;    w += (size_t)T_Q * FNL * 4 * sizeof(int);
    int*   final4 = (int*)w;

    hipLaunchKernelGGL(r2_kernel, dim3(N_REF / 64), dim3(256), 0, stream, R, r2);
    hipLaunchKernelGGL(score_topk_kernel, dim3(N_REF / FBN, T_Q / FBM), dim3(256), 0, stream,
                       X, R, r2, pscore, pidx);
    hipLaunchKernelGGL((select_kernel<FNL>), dim3(T_Q), dim3(64), 0, stream,
                       pscore, pidx, final4);
    hipLaunchKernelGGL(gather_kernel, dim3(T_Q / 64, DIM / 4), dim3(256), 0, stream,
                       R, final4, out);
  }
}